// Round 1
// baseline (4057.203 us; speedup 1.0000x reference)
//
#include <hip/hip_runtime.h>
#include <hip/hip_bf16.h>

#define D 128

// problem sizes (fixed by reference)
#define NU 100000
#define NP 100000
#define NC 1000
#define NB 2000
#define NTOT 203000
#define EB 100000
#define ES 50000
#define ETOT 800000

// ws layout (float offsets)
#define OFF_E    0            // 800000 floats: per-edge logits
#define OFF_MKEY 800000       // 803000 uints: encoded segment max
#define OFF_SSUM 1603000      // 803000 floats: segment softmax denom
#define OFF_L    2406000      // 6448000 floats: low-rank accumulators
#define OFF_W0   8854000      // 10*3*128
#define OFF_W1   8857840      // 10*128
#define OFF_CST  8859120      // 10*3 (padded)

// per-edge-type metadata
__constant__ int c_srcT[10]   = {0,0,0,1,1,1,1,2,1,3};
__constant__ int c_dstT[10]   = {1,1,1,0,0,0,2,1,3,1};
__constant__ int c_phi [10]   = {0,0,0,1,1,1,1,2,1,3};
__constant__ int c_beta[10]   = {0,1,2,0,1,2,-1,-1,-1,-1};
__constant__ int c_E   [10]   = {EB,EB,EB,EB,EB,EB,ES,ES,ES,ES};
__constant__ int c_moff[10]   = {0,100000,200000,300000,400000,500000,600000,601000,701000,703000};
__constant__ int c_dstRow[10] = {100000,100000,100000,0,0,0,200000,100000,201000,100000};
__constant__ int c_Loff[10]   = {0,0,0,1600000,1600000,1600000,3200000,3216000,4816000,4848000};

struct Ptrs {
    const float* x[4];
    const int*   ei[10];
    const int*   attr[4];   // for edge types 6..9
};

__device__ __forceinline__ void decode_et(int eflat, int& et, int& le) {
    if (eflat < 600000) { et = eflat / 100000; le = eflat - et * 100000; }
    else { int r = eflat - 600000; int q = r / 50000; et = 6 + q; le = r - q * 50000; }
}

__device__ __forceinline__ float decode_m(unsigned key) {
    unsigned u = (key & 0x80000000u) ? (key ^ 0x80000000u) : ~key;
    return __uint_as_float(u);
}

// ---------------- K0: precompute per-edge-type tables ----------------
__global__ void k0_tables(const float* __restrict__ Wb, const float* __restrict__ A,
                          const float* __restrict__ B, const float* __restrict__ relW,
                          const float* __restrict__ behW, const float* __restrict__ a_att,
                          float* __restrict__ w0, float* __restrict__ w1,
                          float* __restrict__ cst)
{
    __shared__ float a0[128], a1[128], a2[128], a3[128];
    __shared__ float c0[128], c1[128];
    __shared__ float g0[4][16], g1[4][16];
    __shared__ float rs[10], bs[4];
    int t = threadIdx.x;
    if (t < 128) { a0[t]=a_att[t]; a1[t]=a_att[128+t]; a2[t]=a_att[256+t]; a3[t]=a_att[384+t]; }
    __syncthreads();
    if (t < 128) {
        float s0=0.f, s1=0.f;
        for (int j=0;j<128;j++){ float w=Wb[j*128+t]; s0+=w*a0[j]; s1+=w*a1[j]; }
        c0[t]=s0; c1[t]=s1;
    } else if (t < 192) {
        int q=t-128; int p=q>>4, r=q&15;
        float s0=0.f, s1=0.f;
        for (int i=0;i<128;i++){ float av=A[p*2048+i*16+r]; s0+=av*a0[i]; s1+=av*a1[i]; }
        g0[p][r]=s0; g1[p][r]=s1;
    } else if (t < 202) {
        int ri=t-192; float s=0.f;
        for (int i=0;i<128;i++) s+=relW[ri*128+i]*a2[i];
        rs[ri]=s;
    } else if (t < 206) {
        int b=t-202; float s=0.f;
        for (int i=0;i<128;i++) s+=behW[b*128+i]*a3[i];
        bs[b]=s;
    }
    __syncthreads();
    if (t < 128) {
        for (int et=0; et<10; ++et) {
            int phi=c_phi[et], beta=c_beta[et];
            if (beta >= 0) {
                float s0=c0[t], s1=c1[t];
                for (int r=0;r<16;r++){ float bv=B[beta*2048+t*16+r]; s0+=bv*g0[phi][r]; s1+=bv*g1[phi][r]; }
                w0[et*384+t]=s0;
                w0[et*384+128+t]=s0;   // unused slots, keep defined
                w0[et*384+256+t]=s0;
                w1[et*128+t]=s1;
            } else {
                for (int o=0;o<3;o++){
                    float s0=c0[t];
                    for (int r=0;r<16;r++) s0+=B[o*2048+t*16+r]*g0[phi][r];
                    w0[et*384+o*128+t]=s0;
                }
                w1[et*128+t]=c1[t];
            }
        }
    }
    if (t == 255) {
        for (int et=0;et<10;et++){
            int beta=c_beta[et];
            if (beta>=0){ float v=rs[et]+bs[beta]; cst[et*3]=v; cst[et*3+1]=v; cst[et*3+2]=v; }
            else { for (int o=0;o<3;o++) cst[et*3+o]=rs[et]+bs[o]; }
        }
    }
}

// ---------------- K1: per-edge logit e + segment max ----------------
__global__ __launch_bounds__(256) void k1_escore(Ptrs P, const float* __restrict__ w0,
        const float* __restrict__ w1, const float* __restrict__ cst,
        float* __restrict__ e_all, unsigned* __restrict__ mkey)
{
    int tid = blockIdx.x*256 + threadIdx.x;
    int eflat = tid >> 4, lane = tid & 15;
    if (eflat >= ETOT) return;
    int et, le; decode_et(eflat, et, le);
    const int* ei = P.ei[et];
    int E = c_E[et];
    int src = ei[le], dst = ei[E+le];
    int beta = c_beta[et];
    int o = 0;
    if (beta < 0) { int a = P.attr[et-6][le]; o = min(max(a,0),2); }
    const float* hs = P.x[c_srcT[et]] + (size_t)src*D + lane*8;
    const float* hd = P.x[c_dstT[et]] + (size_t)dst*D + lane*8;
    const float* wa = w0 + et*384 + o*128 + lane*8;
    const float* wb = w1 + et*128 + lane*8;
    float4 h0 = *(const float4*)hs,     h1 = *(const float4*)(hs+4);
    float4 wv0 = *(const float4*)wa,    wv1 = *(const float4*)(wa+4);
    float4 d0 = *(const float4*)hd,     d1 = *(const float4*)(hd+4);
    float4 u0 = *(const float4*)wb,     u1 = *(const float4*)(wb+4);
    float dot = h0.x*wv0.x + h0.y*wv0.y + h0.z*wv0.z + h0.w*wv0.w
              + h1.x*wv1.x + h1.y*wv1.y + h1.z*wv1.z + h1.w*wv1.w
              + d0.x*u0.x  + d0.y*u0.y  + d0.z*u0.z  + d0.w*u0.w
              + d1.x*u1.x  + d1.y*u1.y  + d1.z*u1.z  + d1.w*u1.w;
    #pragma unroll
    for (int mm=1; mm<16; mm<<=1) dot += __shfl_xor(dot, mm, 64);
    if (lane == 0) {
        float e = dot + cst[et*3+o];
        e_all[eflat] = e;
        unsigned u = __float_as_uint(e);
        unsigned key = u ^ (unsigned)(((int)u >> 31) | 0x80000000);
        atomicMax(&mkey[c_moff[et] + dst], key);
    }
}

// ---------------- K2: segment sum of exp(e-m) ----------------
__global__ __launch_bounds__(256) void k2_ssum(Ptrs P, const float* __restrict__ e_all,
        const unsigned* __restrict__ mkey, float* __restrict__ ssum)
{
    int eflat = blockIdx.x*256 + threadIdx.x;
    if (eflat >= ETOT) return;
    int et, le; decode_et(eflat, et, le);
    int dst = P.ei[et][c_E[et] + le];
    int mo = c_moff[et] + dst;
    float m = decode_m(mkey[mo]);
    float ex = expf(e_all[eflat] - m);
    atomicAdd(&ssum[mo], ex);
}

// ---------------- K3: alpha-weighted scatter into S (=d_out) and L ----------------
__global__ __launch_bounds__(256) void k3_scatter(Ptrs P, const float* __restrict__ B,
        const float* __restrict__ e_all, const unsigned* __restrict__ mkey,
        const float* __restrict__ ssum, float* __restrict__ Sout, float* __restrict__ Lb)
{
    int tid = blockIdx.x*256 + threadIdx.x;
    int eflat = tid >> 4, lane = tid & 15;
    if (eflat >= ETOT) return;
    int et, le; decode_et(eflat, et, le);
    const int* ei = P.ei[et];
    int E = c_E[et];
    int src = ei[le], dst = ei[E+le];
    int beta = c_beta[et];
    int o = 0;
    if (beta < 0) { int a = P.attr[et-6][le]; o = min(max(a,0),2); }
    int bsel = beta >= 0 ? beta : o;
    int mo = c_moff[et] + dst;
    float m = decode_m(mkey[mo]);
    float alpha = expf(e_all[eflat] - m) / (ssum[mo] + 1e-16f);

    const float* hs = P.x[c_srcT[et]] + (size_t)src*D + lane*8;
    float4 h0 = *(const float4*)hs, h1 = *(const float4*)(hs+4);
    float h[8] = {h0.x,h0.y,h0.z,h0.w,h1.x,h1.y,h1.z,h1.w};

    // partial t = B[bsel]^T hs over this lane's 8 rows
    float pr[16];
    #pragma unroll
    for (int r=0;r<16;r++) pr[r]=0.f;
    const float* Bp = B + bsel*2048 + lane*8*16;
    #pragma unroll
    for (int k=0;k<8;k++){
        float4 b0 = *(const float4*)(Bp + k*16);
        float4 b1 = *(const float4*)(Bp + k*16 + 4);
        float4 b2 = *(const float4*)(Bp + k*16 + 8);
        float4 b3 = *(const float4*)(Bp + k*16 + 12);
        float hv = h[k];
        pr[0]+=hv*b0.x;  pr[1]+=hv*b0.y;  pr[2]+=hv*b0.z;  pr[3]+=hv*b0.w;
        pr[4]+=hv*b1.x;  pr[5]+=hv*b1.y;  pr[6]+=hv*b1.z;  pr[7]+=hv*b1.w;
        pr[8]+=hv*b2.x;  pr[9]+=hv*b2.y;  pr[10]+=hv*b2.z; pr[11]+=hv*b2.w;
        pr[12]+=hv*b3.x; pr[13]+=hv*b3.y; pr[14]+=hv*b3.z; pr[15]+=hv*b3.w;
    }
    // reduce-scatter butterfly across 16 lanes: lane l ends with t[l] (static indices only)
    float v8[8];
    #pragma unroll
    for (int r=0;r<8;r++){
        float keep = (lane&8) ? pr[r+8] : pr[r];
        float give = (lane&8) ? pr[r]   : pr[r+8];
        v8[r] = keep + __shfl_xor(give, 8, 64);
    }
    float v4[4];
    #pragma unroll
    for (int r=0;r<4;r++){
        float keep = (lane&4) ? v8[r+4] : v8[r];
        float give = (lane&4) ? v8[r]   : v8[r+4];
        v4[r] = keep + __shfl_xor(give, 4, 64);
    }
    float v2[2];
    #pragma unroll
    for (int r=0;r<2;r++){
        float keep = (lane&2) ? v4[r+2] : v4[r];
        float give = (lane&2) ? v4[r]   : v4[r+2];
        v2[r] = keep + __shfl_xor(give, 2, 64);
    }
    float keep = (lane&1) ? v2[1] : v2[0];
    float give = (lane&1) ? v2[0] : v2[1];
    float tmine = keep + __shfl_xor(give, 1, 64);

    float* Srow = Sout + (size_t)(c_dstRow[et] + dst)*D + lane*8;
    #pragma unroll
    for (int k=0;k<8;k++) atomicAdd(Srow+k, alpha*h[k]);
    float* Lrow = Lb + c_Loff[et] + (size_t)dst*16;
    atomicAdd(Lrow + lane, alpha*tmine);
}

// ---------------- K4: agg = W_base@S + sum A[p]@L_p, then LN + ELU + residual ----------------
__global__ __launch_bounds__(256) void k4_final(
        const float* __restrict__ Wb, const float* __restrict__ A,
        const float* __restrict__ Lb, const float* __restrict__ x,
        const float* __restrict__ gamma, const float* __restrict__ lbeta,
        float* __restrict__ out, int rowStart, int nRows,
        int nPairs, int lo0, int ai0, int lo1, int ai1, int lo2, int ai2)
{
    __shared__ float st[64*132];   // 64 rows, stride 132 (pad 4) to break bank conflicts
    int t = threadIdx.x;
    int r0 = blockIdx.x*64;
    for (int idx=t; idx<8192; idx+=256){
        int r = idx>>7, i = idx&127;
        int lr = r0 + r;
        st[r*132+i] = (lr < nRows) ? out[(size_t)(rowStart+lr)*D + i] : 0.f;
    }
    __syncthreads();

    int cg = t & 15, rg = t >> 4;
    int j8 = cg*8;
    float acc[4][8];
    #pragma unroll
    for (int a=0;a<4;a++)
        #pragma unroll
        for (int c=0;c<8;c++) acc[a][c]=0.f;

    // main: acc[rr][c] = sum_i S[row][i] * W_base[j8+c][i]
    for (int i4=0; i4<32; ++i4){
        float4 sv[4];
        #pragma unroll
        for (int rr=0;rr<4;rr++) sv[rr] = *(const float4*)&st[(rg*4+rr)*132 + i4*4];
        #pragma unroll
        for (int c=0;c<8;c++){
            float4 w4 = *(const float4*)&Wb[(size_t)(j8+c)*128 + i4*4];
            #pragma unroll
            for (int rr=0;rr<4;rr++){
                acc[rr][c] += sv[rr].x*w4.x + sv[rr].y*w4.y + sv[rr].z*w4.z + sv[rr].w*w4.w;
            }
        }
    }

    // low-rank pairs: acc[rr][c] += sum_r A[ai][(j8+c)*16+r] * L[row*16+r]
    for (int pi=0; pi<nPairs; ++pi){
        int lo = (pi==0)?lo0:((pi==1)?lo1:lo2);
        int ai = (pi==0)?ai0:((pi==1)?ai1:ai2);
        const float* Ab = A + ai*2048;
        for (int r=0;r<16;++r){
            float av[8];
            #pragma unroll
            for (int c=0;c<8;c++) av[c] = Ab[(j8+c)*16 + r];
            #pragma unroll
            for (int rr=0;rr<4;rr++){
                int lr = r0 + rg*4 + rr;
                float lv = (lr < nRows) ? Lb[lo + (size_t)lr*16 + r] : 0.f;
                #pragma unroll
                for (int c=0;c<8;c++) acc[rr][c] += av[c]*lv;
            }
        }
    }

    float4 g0v = *(const float4*)&gamma[j8], g1v = *(const float4*)&gamma[j8+4];
    float4 b0v = *(const float4*)&lbeta[j8], b1v = *(const float4*)&lbeta[j8+4];
    float gv[8] = {g0v.x,g0v.y,g0v.z,g0v.w,g1v.x,g1v.y,g1v.z,g1v.w};
    float bv[8] = {b0v.x,b0v.y,b0v.z,b0v.w,b1v.x,b1v.y,b1v.z,b1v.w};

    #pragma unroll
    for (int rr=0;rr<4;rr++){
        int lr = r0 + rg*4 + rr;
        float lsum=0.f, lsq=0.f;
        #pragma unroll
        for (int c=0;c<8;c++){ lsum += acc[rr][c]; lsq += acc[rr][c]*acc[rr][c]; }
        #pragma unroll
        for (int mm=1; mm<16; mm<<=1){ lsum += __shfl_xor(lsum,mm,64); lsq += __shfl_xor(lsq,mm,64); }
        if (lr >= nRows) continue;
        float mu = lsum*(1.f/128.f);
        float var = lsq*(1.f/128.f) - mu*mu;
        float rstd = rsqrtf(var + 1e-5f);
        const float* xr = x + (size_t)lr*D + j8;
        float4 xA = *(const float4*)xr, xB = *(const float4*)(xr+4);
        float xv[8] = {xA.x,xA.y,xA.z,xA.w,xB.x,xB.y,xB.z,xB.w};
        float ov[8];
        #pragma unroll
        for (int c=0;c<8;c++){
            float hn = (acc[rr][c]-mu)*rstd*gv[c] + bv[c];
            float z = hn + xv[c];
            ov[c] = z > 0.f ? z : expm1f(z);
        }
        float* orow = out + (size_t)(rowStart+lr)*D + j8;
        *(float4*)orow     = make_float4(ov[0],ov[1],ov[2],ov[3]);
        *(float4*)(orow+4) = make_float4(ov[4],ov[5],ov[6],ov[7]);
    }
}

extern "C" void kernel_launch(void* const* d_in, const int* in_sizes, int n_in,
                              void* d_out, int out_size, void* d_ws, size_t ws_size,
                              hipStream_t stream)
{
    (void)in_sizes; (void)n_in; (void)out_size; (void)ws_size;
    Ptrs P;
    P.x[0] = (const float*)d_in[0];   // x_user
    P.x[1] = (const float*)d_in[1];   // x_product
    P.x[2] = (const float*)d_in[2];   // x_category
    P.x[3] = (const float*)d_in[3];   // x_brand
    P.ei[0] = (const int*)d_in[4];    // view
    P.ei[1] = (const int*)d_in[5];    // cart
    P.ei[2] = (const int*)d_in[6];    // purchase
    P.ei[3] = (const int*)d_in[7];    // rev_view
    P.ei[4] = (const int*)d_in[8];    // rev_cart
    P.ei[5] = (const int*)d_in[9];    // rev_purchase
    P.ei[6] = (const int*)d_in[10];   // belongs_to
    P.attr[0] = (const int*)d_in[11];
    P.ei[7] = (const int*)d_in[12];   // contains
    P.attr[1] = (const int*)d_in[13];
    P.ei[8] = (const int*)d_in[14];   // producedBy
    P.attr[2] = (const int*)d_in[15];
    P.ei[9] = (const int*)d_in[16];   // brands
    P.attr[3] = (const int*)d_in[17];
    const float* Wb    = (const float*)d_in[18];
    const float* A     = (const float*)d_in[19];
    const float* B     = (const float*)d_in[20];
    const float* relW  = (const float*)d_in[21];
    const float* behW  = (const float*)d_in[22];
    const float* a_att = (const float*)d_in[23];
    const float* gamma = (const float*)d_in[24];
    const float* lbeta = (const float*)d_in[25];
    float* wsf = (float*)d_ws;
    float* out = (float*)d_out;

    // zero S (=d_out), segment-max keys, softmax denoms, low-rank accumulators
    hipMemsetAsync(out, 0, (size_t)NTOT*D*sizeof(float), stream);
    hipMemsetAsync(wsf + OFF_MKEY, 0, (size_t)(OFF_W0 - OFF_MKEY)*sizeof(float), stream);

    k0_tables<<<1, 256, 0, stream>>>(Wb, A, B, relW, behW, a_att,
                                     wsf+OFF_W0, wsf+OFF_W1, wsf+OFF_CST);
    k1_escore<<<50000, 256, 0, stream>>>(P, wsf+OFF_W0, wsf+OFF_W1, wsf+OFF_CST,
                                         wsf+OFF_E, (unsigned*)(wsf+OFF_MKEY));
    k2_ssum<<<3125, 256, 0, stream>>>(P, wsf+OFF_E, (unsigned*)(wsf+OFF_MKEY), wsf+OFF_SSUM);
    k3_scatter<<<50000, 256, 0, stream>>>(P, B, wsf+OFF_E, (unsigned*)(wsf+OFF_MKEY),
                                          wsf+OFF_SSUM, out, wsf+OFF_L);
    // epilogue per node type: rowStart, nRows, pairs {(Loff, A-index)}
    k4_final<<<(NU+63)/64, 256, 0, stream>>>(Wb, A, wsf+OFF_L, P.x[0], gamma, lbeta, out,
                                             0,      NU, 1, 1600000,1, 0,0, 0,0);
    k4_final<<<(NP+63)/64, 256, 0, stream>>>(Wb, A, wsf+OFF_L, P.x[1], gamma, lbeta, out,
                                             100000, NP, 3, 0,0, 3216000,2, 4848000,3);
    k4_final<<<(NC+63)/64, 256, 0, stream>>>(Wb, A, wsf+OFF_L, P.x[2], gamma, lbeta, out,
                                             200000, NC, 1, 3200000,1, 0,0, 0,0);
    k4_final<<<(NB+63)/64, 256, 0, stream>>>(Wb, A, wsf+OFF_L, P.x[3], gamma, lbeta, out,
                                             201000, NB, 1, 4816000,1, 0,0, 0,0);
}

// Round 2
// 2161.480 us; speedup vs baseline: 1.8770x; 1.8770x over previous
//
#include <hip/hip_runtime.h>
#include <hip/hip_bf16.h>
#include <math.h>

#define D 128

// problem sizes (fixed by reference)
#define NU 100000
#define NP 100000
#define NC 1000
#define NB 2000
#define NTOT 203000
#define EB 100000
#define ES 50000
#define ETOT 800000
#define NSEG 803000
#define NBLK 785          // ceil(NSEG/1024)

// ws layout (float offsets)
#define OFF_L    0            // 6448000 floats: low-rank accumulators (per group regions)
#define OFF_W0   6448000      // 10*3*128
#define OFF_W1   6451840      // 10*128
#define OFF_CST  6453120      // 10*3 (padded to 32)
#define OFF_INT  6453152      // int region start
// ints relative to (int*)(wsf+OFF_INT):
//   counts @ 0        (803000)
//   starts @ 803000   (803000)
//   elist  @ 1606000  (800000)
// bsums (785 ints) overlays OFF_L (only used before kgather rewrites L)

// per-edge-type metadata
__constant__ int c_srcT[10]   = {0,0,0,1,1,1,1,2,1,3};
__constant__ int c_phi [10]   = {0,0,0,1,1,1,1,2,1,3};
__constant__ int c_beta[10]   = {0,1,2,0,1,2,-1,-1,-1,-1};
__constant__ int c_E   [10]   = {EB,EB,EB,EB,EB,EB,ES,ES,ES,ES};
__constant__ int c_moff[10]   = {0,100000,200000,300000,400000,500000,600000,601000,701000,703000};

// per-dst-type gather config
__constant__ int g_nEt[4]     = {3,5,1,1};
__constant__ int g_ets[4][5]  = {{3,4,5,0,0},{0,1,2,7,9},{6,0,0,0,0},{8,0,0,0,0}};
__constant__ int g_gidx[4][5] = {{0,0,0,0,0},{0,0,0,1,2},{0,0,0,0,0},{0,0,0,0,0}};
__constant__ int g_nGrp[4]    = {1,3,1,1};
__constant__ int g_Loff[4][3] = {{1600000,0,0},{0,3216000,4848000},{3200000,0,0},{4816000,0,0}};

struct Ptrs {
    const float* x[4];
    const int*   ei[10];
    const int*   attr[4];   // for edge types 6..9
};

__device__ __forceinline__ void decode_et(int eflat, int& et, int& le) {
    if (eflat < 600000) { et = eflat / 100000; le = eflat - et * 100000; }
    else { int r = eflat - 600000; int q = r / 50000; et = 6 + q; le = r - q * 50000; }
}

// sum across the 16-lane quarter-wave group
__device__ __forceinline__ float qsum(float v) {
    v += __shfl_xor(v, 1, 64);
    v += __shfl_xor(v, 2, 64);
    v += __shfl_xor(v, 4, 64);
    v += __shfl_xor(v, 8, 64);
    return v;
}

// reduce-scatter butterfly across 16 lanes: returns element `lane` of the
// 16-vector sum over the 16-lane group's partials (static reg indices only)
__device__ __forceinline__ float reduce_scatter16(const float pr[16], int lane) {
    float v8[8];
    #pragma unroll
    for (int r=0;r<8;r++){
        float keep = (lane&8) ? pr[r+8] : pr[r];
        float give = (lane&8) ? pr[r]   : pr[r+8];
        v8[r] = keep + __shfl_xor(give, 8, 64);
    }
    float v4[4];
    #pragma unroll
    for (int r=0;r<4;r++){
        float keep = (lane&4) ? v8[r+4] : v8[r];
        float give = (lane&4) ? v8[r]   : v8[r+4];
        v4[r] = keep + __shfl_xor(give, 4, 64);
    }
    float v2[2];
    #pragma unroll
    for (int r=0;r<2;r++){
        float keep = (lane&2) ? v4[r+2] : v4[r];
        float give = (lane&2) ? v4[r]   : v4[r+2];
        v2[r] = keep + __shfl_xor(give, 2, 64);
    }
    float keep = (lane&1) ? v2[1] : v2[0];
    float give = (lane&1) ? v2[0] : v2[1];
    return keep + __shfl_xor(give, 1, 64);
}

// ---------------- K0: precompute per-edge-type tables ----------------
__global__ void k0_tables(const float* __restrict__ Wb, const float* __restrict__ A,
                          const float* __restrict__ B, const float* __restrict__ relW,
                          const float* __restrict__ behW, const float* __restrict__ a_att,
                          float* __restrict__ w0, float* __restrict__ w1,
                          float* __restrict__ cst)
{
    __shared__ float a0[128], a1[128], a2[128], a3[128];
    __shared__ float c0[128], c1[128];
    __shared__ float g0[4][16], g1[4][16];
    __shared__ float rs[10], bs[4];
    int t = threadIdx.x;
    if (t < 128) { a0[t]=a_att[t]; a1[t]=a_att[128+t]; a2[t]=a_att[256+t]; a3[t]=a_att[384+t]; }
    __syncthreads();
    if (t < 128) {
        float s0=0.f, s1=0.f;
        for (int j=0;j<128;j++){ float w=Wb[j*128+t]; s0+=w*a0[j]; s1+=w*a1[j]; }
        c0[t]=s0; c1[t]=s1;
    } else if (t < 192) {
        int q=t-128; int p=q>>4, r=q&15;
        float s0=0.f, s1=0.f;
        for (int i=0;i<128;i++){ float av=A[p*2048+i*16+r]; s0+=av*a0[i]; s1+=av*a1[i]; }
        g0[p][r]=s0; g1[p][r]=s1;
    } else if (t < 202) {
        int ri=t-192; float s=0.f;
        for (int i=0;i<128;i++) s+=relW[ri*128+i]*a2[i];
        rs[ri]=s;
    } else if (t < 206) {
        int b=t-202; float s=0.f;
        for (int i=0;i<128;i++) s+=behW[b*128+i]*a3[i];
        bs[b]=s;
    }
    __syncthreads();
    if (t < 128) {
        for (int et=0; et<10; ++et) {
            int phi=c_phi[et], beta=c_beta[et];
            if (beta >= 0) {
                float s0=c0[t], s1=c1[t];
                for (int r=0;r<16;r++){ float bv=B[beta*2048+t*16+r]; s0+=bv*g0[phi][r]; s1+=bv*g1[phi][r]; }
                w0[et*384+t]=s0;
                w0[et*384+128+t]=s0;
                w0[et*384+256+t]=s0;
                w1[et*128+t]=s1;
            } else {
                for (int o=0;o<3;o++){
                    float s0=c0[t];
                    for (int r=0;r<16;r++) s0+=B[o*2048+t*16+r]*g0[phi][r];
                    w0[et*384+o*128+t]=s0;
                }
                w1[et*128+t]=c1[t];
            }
        }
    }
    if (t == 255) {
        for (int et=0;et<10;et++){
            int beta=c_beta[et];
            if (beta>=0){ float v=rs[et]+bs[beta]; cst[et*3]=v; cst[et*3+1]=v; cst[et*3+2]=v; }
            else { for (int o=0;o<3;o++) cst[et*3+o]=rs[et]+bs[o]; }
        }
    }
}

// ---------------- CSR build ----------------
__global__ __launch_bounds__(256) void khist(Ptrs P, int* __restrict__ counts)
{
    int eflat = blockIdx.x*256 + threadIdx.x;
    if (eflat >= ETOT) return;
    int et, le; decode_et(eflat, et, le);
    int dst = P.ei[et][c_E[et] + le];
    atomicAdd(&counts[c_moff[et] + dst], 1);
}

__global__ __launch_bounds__(256) void kscan1(const int* __restrict__ cnt,
                                              int* __restrict__ st, int* __restrict__ bsums)
{
    __shared__ int lds[256];
    int t = threadIdx.x, b = blockIdx.x;
    int base = b*1024 + t*4;
    int v0 = (base   < NSEG) ? cnt[base]   : 0;
    int v1 = (base+1 < NSEG) ? cnt[base+1] : 0;
    int v2 = (base+2 < NSEG) ? cnt[base+2] : 0;
    int v3 = (base+3 < NSEG) ? cnt[base+3] : 0;
    int s = v0+v1+v2+v3;
    lds[t] = s; __syncthreads();
    for (int off=1; off<256; off<<=1){
        int xv = (t>=off) ? lds[t-off] : 0;
        __syncthreads();
        lds[t] += xv;
        __syncthreads();
    }
    int incl = lds[t];
    int p = incl - s;
    if (t==255) bsums[b] = incl;
    if (base   < NSEG) st[base]   = p; p += v0;
    if (base+1 < NSEG) st[base+1] = p; p += v1;
    if (base+2 < NSEG) st[base+2] = p; p += v2;
    if (base+3 < NSEG) st[base+3] = p;
}

__global__ __launch_bounds__(256) void kscan2(int* __restrict__ bsums)
{
    __shared__ int lds[256];
    int t = threadIdx.x;
    int base = t*4;
    int v0 = (base   < NBLK) ? bsums[base]   : 0;
    int v1 = (base+1 < NBLK) ? bsums[base+1] : 0;
    int v2 = (base+2 < NBLK) ? bsums[base+2] : 0;
    int v3 = (base+3 < NBLK) ? bsums[base+3] : 0;
    int s = v0+v1+v2+v3;
    lds[t] = s; __syncthreads();
    for (int off=1; off<256; off<<=1){
        int xv = (t>=off) ? lds[t-off] : 0;
        __syncthreads();
        lds[t] += xv;
        __syncthreads();
    }
    int p = lds[t] - s;
    if (base   < NBLK) bsums[base]   = p; p += v0;
    if (base+1 < NBLK) bsums[base+1] = p; p += v1;
    if (base+2 < NBLK) bsums[base+2] = p; p += v2;
    if (base+3 < NBLK) bsums[base+3] = p;
}

__global__ __launch_bounds__(256) void kscan3(int* __restrict__ st, const int* __restrict__ bsums)
{
    int t = threadIdx.x, b = blockIdx.x;
    int add = bsums[b];
    int base = b*1024 + t*4;
    #pragma unroll
    for (int j=0;j<4;j++)
        if (base+j < NSEG) st[base+j] += add;
}

__global__ __launch_bounds__(256) void kscatter(Ptrs P, int* __restrict__ st, int* __restrict__ elist)
{
    int eflat = blockIdx.x*256 + threadIdx.x;
    if (eflat >= ETOT) return;
    int et, le; decode_et(eflat, et, le);
    int dst = P.ei[et][c_E[et] + le];
    int pos = atomicAdd(&st[c_moff[et] + dst], 1);
    elist[pos] = le;
}
// after kscatter: st[seg] == segment end; start = st[seg] - counts[seg]

// ---------------- kgather: per-dst-node online softmax + aggregate ----------------
// 16 lanes per node; writes S row (into out, as staging) and per-group L vectors.
__global__ __launch_bounds__(256) void kgather(int T, int nNodes, int rowStart, Ptrs P,
        const float* __restrict__ w0, const float* __restrict__ w1, const float* __restrict__ cst,
        const int* __restrict__ starts, const int* __restrict__ counts, const int* __restrict__ elist,
        const float* __restrict__ Bm, float* __restrict__ Sout, float* __restrict__ Lb)
{
    int t = threadIdx.x;
    int lane = t & 15, g = t >> 4;
    int n = blockIdx.x*16 + g;
    bool act = n < nNodes;

    float hdv[8] = {0,0,0,0,0,0,0,0};
    if (act) {
        const float* hp = P.x[T] + (size_t)n*D + lane*8;
        float4 a4 = *(const float4*)hp, b4 = *(const float4*)(hp+4);
        hdv[0]=a4.x; hdv[1]=a4.y; hdv[2]=a4.z; hdv[3]=a4.w;
        hdv[4]=b4.x; hdv[5]=b4.y; hdv[6]=b4.z; hdv[7]=b4.w;
    }
    float Stot[8] = {0,0,0,0,0,0,0,0};
    float Lg0=0.f, Lg1=0.f, Lg2=0.f;

    int nEt = g_nEt[T];
    if (act) {
        for (int s=0; s<nEt; ++s) {
            int et = g_ets[T][s];
            int beta = c_beta[et];
            bool structural = (beta < 0);
            const float* xs = P.x[c_srcT[et]];
            const int* ei = P.ei[et];
            const int* attr = structural ? P.attr[et-6] : (const int*)0;
            int seg = c_moff[et] + n;
            int end = starts[seg];
            int cnt = counts[seg];
            int st0 = end - cnt;
            if (cnt == 0) continue;

            // preload w0 vectors (up to 3 origins) and cst scalars
            const float* w0p = w0 + et*384 + lane*8;
            float wv0[8], wv1[8], wv2[8];
            {
                float4 a4 = *(const float4*)w0p, b4 = *(const float4*)(w0p+4);
                wv0[0]=a4.x;wv0[1]=a4.y;wv0[2]=a4.z;wv0[3]=a4.w;
                wv0[4]=b4.x;wv0[5]=b4.y;wv0[6]=b4.z;wv0[7]=b4.w;
            }
            if (structural) {
                float4 a4 = *(const float4*)(w0p+128), b4 = *(const float4*)(w0p+132);
                wv1[0]=a4.x;wv1[1]=a4.y;wv1[2]=a4.z;wv1[3]=a4.w;
                wv1[4]=b4.x;wv1[5]=b4.y;wv1[6]=b4.z;wv1[7]=b4.w;
                float4 c4 = *(const float4*)(w0p+256), d4 = *(const float4*)(w0p+260);
                wv2[0]=c4.x;wv2[1]=c4.y;wv2[2]=c4.z;wv2[3]=c4.w;
                wv2[4]=d4.x;wv2[5]=d4.y;wv2[6]=d4.z;wv2[7]=d4.w;
            } else {
                #pragma unroll
                for (int j=0;j<8;j++){ wv1[j]=wv0[j]; wv2[j]=wv0[j]; }
            }
            float cst0 = cst[et*3], cst1 = cst[et*3+1], cst2 = cst[et*3+2];

            // hd . w1[et]
            const float* w1p = w1 + et*128 + lane*8;
            float hw;
            {
                float4 a4 = *(const float4*)w1p, b4 = *(const float4*)(w1p+4);
                hw = hdv[0]*a4.x + hdv[1]*a4.y + hdv[2]*a4.z + hdv[3]*a4.w
                   + hdv[4]*b4.x + hdv[5]*b4.y + hdv[6]*b4.z + hdv[7]*b4.w;
                hw = qsum(hw);
            }

            float m = -INFINITY, ssum = 0.f, La = 0.f;
            float Sacc[8] = {0,0,0,0,0,0,0,0};

            int le = elist[st0];
            int src = ei[le];
            for (int k=0; k<cnt; ++k) {
                int le_n = 0, src_n = 0;
                if (k+1 < cnt) { le_n = elist[st0+k+1]; src_n = ei[le_n]; }
                int o = 0;
                if (structural) { int a = attr[le]; o = min(max(a,0),2); }

                const float* hp = xs + (size_t)src*D + lane*8;
                float4 hA = *(const float4*)hp, hB = *(const float4*)(hp+4);
                float h[8] = {hA.x,hA.y,hA.z,hA.w,hB.x,hB.y,hB.z,hB.w};

                float d = 0.f;
                #pragma unroll
                for (int j=0;j<8;j++){
                    float wj = (o==0) ? wv0[j] : ((o==1) ? wv1[j] : wv2[j]);
                    d += h[j]*wj;
                }
                float csel = (o==0) ? cst0 : ((o==1) ? cst1 : cst2);
                float e = qsum(d) + hw + csel;

                float mn = fmaxf(m, e);
                float sc = expf(m - mn);
                float wg = expf(e - mn);
                ssum = ssum*sc + wg;
                #pragma unroll
                for (int j=0;j<8;j++) Sacc[j] = Sacc[j]*sc + wg*h[j];

                if (structural) {
                    float pr[16];
                    #pragma unroll
                    for (int r=0;r<16;r++) pr[r]=0.f;
                    const float* Bp = Bm + o*2048 + lane*128;
                    #pragma unroll
                    for (int j=0;j<8;j++){
                        float4 b0 = *(const float4*)(Bp + j*16);
                        float4 b1 = *(const float4*)(Bp + j*16 + 4);
                        float4 b2 = *(const float4*)(Bp + j*16 + 8);
                        float4 b3 = *(const float4*)(Bp + j*16 + 12);
                        float hv = h[j];
                        pr[0]+=hv*b0.x;  pr[1]+=hv*b0.y;  pr[2]+=hv*b0.z;  pr[3]+=hv*b0.w;
                        pr[4]+=hv*b1.x;  pr[5]+=hv*b1.y;  pr[6]+=hv*b1.z;  pr[7]+=hv*b1.w;
                        pr[8]+=hv*b2.x;  pr[9]+=hv*b2.y;  pr[10]+=hv*b2.z; pr[11]+=hv*b2.w;
                        pr[12]+=hv*b3.x; pr[13]+=hv*b3.y; pr[14]+=hv*b3.z; pr[15]+=hv*b3.w;
                    }
                    float tl = reduce_scatter16(pr, lane);
                    La = La*sc + wg*tl;
                }
                m = mn;
                le = le_n; src = src_n;
            }

            float inv = 1.f/(ssum + 1e-16f);
            #pragma unroll
            for (int j=0;j<8;j++){ float sn = Sacc[j]*inv; Stot[j] += sn; Sacc[j] = sn; }

            float addv;
            if (structural) addv = La*inv;
            else {
                // B[beta]^T Snorm via reduce-scatter
                float pr[16];
                #pragma unroll
                for (int r=0;r<16;r++) pr[r]=0.f;
                const float* Bp = Bm + beta*2048 + lane*128;
                #pragma unroll
                for (int j=0;j<8;j++){
                    float4 b0 = *(const float4*)(Bp + j*16);
                    float4 b1 = *(const float4*)(Bp + j*16 + 4);
                    float4 b2 = *(const float4*)(Bp + j*16 + 8);
                    float4 b3 = *(const float4*)(Bp + j*16 + 12);
                    float hv = Sacc[j];
                    pr[0]+=hv*b0.x;  pr[1]+=hv*b0.y;  pr[2]+=hv*b0.z;  pr[3]+=hv*b0.w;
                    pr[4]+=hv*b1.x;  pr[5]+=hv*b1.y;  pr[6]+=hv*b1.z;  pr[7]+=hv*b1.w;
                    pr[8]+=hv*b2.x;  pr[9]+=hv*b2.y;  pr[10]+=hv*b2.z; pr[11]+=hv*b2.w;
                    pr[12]+=hv*b3.x; pr[13]+=hv*b3.y; pr[14]+=hv*b3.z; pr[15]+=hv*b3.w;
                }
                addv = reduce_scatter16(pr, lane);
            }
            int gi = g_gidx[T][s];
            if (gi==0) Lg0 += addv; else if (gi==1) Lg1 += addv; else Lg2 += addv;
        }
    }

    if (act) {
        float* Srow = Sout + (size_t)(rowStart + n)*D + lane*8;
        *(float4*)Srow     = make_float4(Stot[0],Stot[1],Stot[2],Stot[3]);
        *(float4*)(Srow+4) = make_float4(Stot[4],Stot[5],Stot[6],Stot[7]);
        int ng = g_nGrp[T];
        Lb[g_Loff[T][0] + (size_t)n*16 + lane] = Lg0;
        if (ng > 1) Lb[g_Loff[T][1] + (size_t)n*16 + lane] = Lg1;
        if (ng > 2) Lb[g_Loff[T][2] + (size_t)n*16 + lane] = Lg2;
    }
}

// ---------------- K4: agg = W_base@S + sum A[p]@L_p, then LN + ELU + residual ----------------
__global__ __launch_bounds__(256) void k4_final(
        const float* __restrict__ Wb, const float* __restrict__ A,
        const float* __restrict__ Lb, const float* __restrict__ x,
        const float* __restrict__ gamma, const float* __restrict__ lbeta,
        float* __restrict__ out, int rowStart, int nRows,
        int nPairs, int lo0, int ai0, int lo1, int ai1, int lo2, int ai2)
{
    __shared__ float st[64*132];   // 64 rows, stride 132 (pad 4) to break bank conflicts
    int t = threadIdx.x;
    int r0 = blockIdx.x*64;
    for (int idx=t; idx<8192; idx+=256){
        int r = idx>>7, i = idx&127;
        int lr = r0 + r;
        st[r*132+i] = (lr < nRows) ? out[(size_t)(rowStart+lr)*D + i] : 0.f;
    }
    __syncthreads();

    int cg = t & 15, rg = t >> 4;
    int j8 = cg*8;
    float acc[4][8];
    #pragma unroll
    for (int a=0;a<4;a++)
        #pragma unroll
        for (int c=0;c<8;c++) acc[a][c]=0.f;

    for (int i4=0; i4<32; ++i4){
        float4 sv[4];
        #pragma unroll
        for (int rr=0;rr<4;rr++) sv[rr] = *(const float4*)&st[(rg*4+rr)*132 + i4*4];
        #pragma unroll
        for (int c=0;c<8;c++){
            float4 w4 = *(const float4*)&Wb[(size_t)(j8+c)*128 + i4*4];
            #pragma unroll
            for (int rr=0;rr<4;rr++){
                acc[rr][c] += sv[rr].x*w4.x + sv[rr].y*w4.y + sv[rr].z*w4.z + sv[rr].w*w4.w;
            }
        }
    }

    for (int pi=0; pi<nPairs; ++pi){
        int lo = (pi==0)?lo0:((pi==1)?lo1:lo2);
        int ai = (pi==0)?ai0:((pi==1)?ai1:ai2);
        const float* Ab = A + ai*2048;
        for (int r=0;r<16;++r){
            float av[8];
            #pragma unroll
            for (int c=0;c<8;c++) av[c] = Ab[(j8+c)*16 + r];
            #pragma unroll
            for (int rr=0;rr<4;rr++){
                int lr = r0 + rg*4 + rr;
                float lv = (lr < nRows) ? Lb[lo + (size_t)lr*16 + r] : 0.f;
                #pragma unroll
                for (int c=0;c<8;c++) acc[rr][c] += av[c]*lv;
            }
        }
    }

    float4 g0v = *(const float4*)&gamma[j8], g1v = *(const float4*)&gamma[j8+4];
    float4 b0v = *(const float4*)&lbeta[j8], b1v = *(const float4*)&lbeta[j8+4];
    float gv[8] = {g0v.x,g0v.y,g0v.z,g0v.w,g1v.x,g1v.y,g1v.z,g1v.w};
    float bv[8] = {b0v.x,b0v.y,b0v.z,b0v.w,b1v.x,b1v.y,b1v.z,b1v.w};

    #pragma unroll
    for (int rr=0;rr<4;rr++){
        int lr = r0 + rg*4 + rr;
        float lsum=0.f, lsq=0.f;
        #pragma unroll
        for (int c=0;c<8;c++){ lsum += acc[rr][c]; lsq += acc[rr][c]*acc[rr][c]; }
        #pragma unroll
        for (int mm=1; mm<16; mm<<=1){ lsum += __shfl_xor(lsum,mm,64); lsq += __shfl_xor(lsq,mm,64); }
        if (lr >= nRows) continue;
        float mu = lsum*(1.f/128.f);
        float var = lsq*(1.f/128.f) - mu*mu;
        float rstd = rsqrtf(var + 1e-5f);
        const float* xr = x + (size_t)lr*D + j8;
        float4 xA = *(const float4*)xr, xB = *(const float4*)(xr+4);
        float xv[8] = {xA.x,xA.y,xA.z,xA.w,xB.x,xB.y,xB.z,xB.w};
        float ov[8];
        #pragma unroll
        for (int c=0;c<8;c++){
            float hn = (acc[rr][c]-mu)*rstd*gv[c] + bv[c];
            float z = hn + xv[c];
            ov[c] = z > 0.f ? z : expm1f(z);
        }
        float* orow = out + (size_t)(rowStart+lr)*D + j8;
        *(float4*)orow     = make_float4(ov[0],ov[1],ov[2],ov[3]);
        *(float4*)(orow+4) = make_float4(ov[4],ov[5],ov[6],ov[7]);
    }
}

extern "C" void kernel_launch(void* const* d_in, const int* in_sizes, int n_in,
                              void* d_out, int out_size, void* d_ws, size_t ws_size,
                              hipStream_t stream)
{
    (void)in_sizes; (void)n_in; (void)out_size; (void)ws_size;
    Ptrs P;
    P.x[0] = (const float*)d_in[0];   // x_user
    P.x[1] = (const float*)d_in[1];   // x_product
    P.x[2] = (const float*)d_in[2];   // x_category
    P.x[3] = (const float*)d_in[3];   // x_brand
    P.ei[0] = (const int*)d_in[4];    // view
    P.ei[1] = (const int*)d_in[5];    // cart
    P.ei[2] = (const int*)d_in[6];    // purchase
    P.ei[3] = (const int*)d_in[7];    // rev_view
    P.ei[4] = (const int*)d_in[8];    // rev_cart
    P.ei[5] = (const int*)d_in[9];    // rev_purchase
    P.ei[6] = (const int*)d_in[10];   // belongs_to
    P.attr[0] = (const int*)d_in[11];
    P.ei[7] = (const int*)d_in[12];   // contains
    P.attr[1] = (const int*)d_in[13];
    P.ei[8] = (const int*)d_in[14];   // producedBy
    P.attr[2] = (const int*)d_in[15];
    P.ei[9] = (const int*)d_in[16];   // brands
    P.attr[3] = (const int*)d_in[17];
    const float* Wb    = (const float*)d_in[18];
    const float* A     = (const float*)d_in[19];
    const float* B     = (const float*)d_in[20];
    const float* relW  = (const float*)d_in[21];
    const float* behW  = (const float*)d_in[22];
    const float* a_att = (const float*)d_in[23];
    const float* gamma = (const float*)d_in[24];
    const float* lbeta = (const float*)d_in[25];
    float* wsf = (float*)d_ws;
    float* out = (float*)d_out;

    int* ip     = (int*)(wsf + OFF_INT);
    int* counts = ip;
    int* starts = ip + 803000;
    int* elist  = ip + 1606000;
    int* bsums  = (int*)wsf;          // overlays L region, used only pre-gather

    hipMemsetAsync(counts, 0, (size_t)NSEG*sizeof(int), stream);

    k0_tables<<<1, 256, 0, stream>>>(Wb, A, B, relW, behW, a_att,
                                     wsf+OFF_W0, wsf+OFF_W1, wsf+OFF_CST);
    khist<<<3125, 256, 0, stream>>>(P, counts);
    kscan1<<<NBLK, 256, 0, stream>>>(counts, starts, bsums);
    kscan2<<<1, 256, 0, stream>>>(bsums);
    kscan3<<<NBLK, 256, 0, stream>>>(starts, bsums);
    kscatter<<<3125, 256, 0, stream>>>(P, starts, elist);

    kgather<<<(NU+15)/16, 256, 0, stream>>>(0, NU, 0,      P, wsf+OFF_W0, wsf+OFF_W1, wsf+OFF_CST,
                                            starts, counts, elist, B, out, wsf+OFF_L);
    kgather<<<(NP+15)/16, 256, 0, stream>>>(1, NP, 100000, P, wsf+OFF_W0, wsf+OFF_W1, wsf+OFF_CST,
                                            starts, counts, elist, B, out, wsf+OFF_L);
    kgather<<<(NC+15)/16, 256, 0, stream>>>(2, NC, 200000, P, wsf+OFF_W0, wsf+OFF_W1, wsf+OFF_CST,
                                            starts, counts, elist, B, out, wsf+OFF_L);
    kgather<<<(NB+15)/16, 256, 0, stream>>>(3, NB, 201000, P, wsf+OFF_W0, wsf+OFF_W1, wsf+OFF_CST,
                                            starts, counts, elist, B, out, wsf+OFF_L);

    k4_final<<<(NU+63)/64, 256, 0, stream>>>(Wb, A, wsf+OFF_L, P.x[0], gamma, lbeta, out,
                                             0,      NU, 1, 1600000,1, 0,0, 0,0);
    k4_final<<<(NP+63)/64, 256, 0, stream>>>(Wb, A, wsf+OFF_L, P.x[1], gamma, lbeta, out,
                                             100000, NP, 3, 0,0, 3216000,2, 4848000,3);
    k4_final<<<(NC+63)/64, 256, 0, stream>>>(Wb, A, wsf+OFF_L, P.x[2], gamma, lbeta, out,
                                             200000, NC, 1, 3200000,1, 0,0, 0,0);
    k4_final<<<(NB+63)/64, 256, 0, stream>>>(Wb, A, wsf+OFF_L, P.x[3], gamma, lbeta, out,
                                             201000, NB, 1, 4816000,1, 0,0, 0,0);
}

// Round 3
// 1481.402 us; speedup vs baseline: 2.7388x; 1.4591x over previous
//
#include <hip/hip_runtime.h>
#include <hip/hip_bf16.h>
#include <math.h>

#define D 128

// problem sizes (fixed by reference)
#define NU 100000
#define NP 100000
#define NC 1000
#define NB 2000
#define NTOT 203000
#define EB 100000
#define ES 50000
#define ETOT 800000
#define NSEG 803000
#define NBLK 785          // ceil(NSEG/1024)

// ws layout (float offsets)
#define OFF_L    0            // 6448000 floats: low-rank accumulators (per group regions)
#define OFF_W0   6448000      // 10*3*128
#define OFF_W1   6451840      // 10*128
#define OFF_CST  6453120      // 10*3 (padded to 32)
#define OFF_INT  6453152      // int region start (2406000 ints)
#define OFF_WT   8859200      // 16384 floats: W_base^T
#define OFF_AT   8875584      // 8192 floats: A^T per phi: AT[p][r][j]
// ints relative to (int*)(wsf+OFF_INT):
//   counts @ 0        (803000)
//   starts @ 803000   (803000)
//   elist  @ 1606000  (800000)
// bsums (785 ints) overlays OFF_L (only used before kgather rewrites L)

// per-edge-type metadata
__constant__ int c_srcT[10]   = {0,0,0,1,1,1,1,2,1,3};
__constant__ int c_phi [10]   = {0,0,0,1,1,1,1,2,1,3};
__constant__ int c_beta[10]   = {0,1,2,0,1,2,-1,-1,-1,-1};
__constant__ int c_E   [10]   = {EB,EB,EB,EB,EB,EB,ES,ES,ES,ES};
__constant__ int c_moff[10]   = {0,100000,200000,300000,400000,500000,600000,601000,701000,703000};

// per-dst-type gather config
__constant__ int g_nEt[4]     = {3,5,1,1};
__constant__ int g_ets[4][5]  = {{3,4,5,0,0},{0,1,2,7,9},{6,0,0,0,0},{8,0,0,0,0}};
__constant__ int g_gidx[4][5] = {{0,0,0,0,0},{0,0,0,1,2},{0,0,0,0,0},{0,0,0,0,0}};
__constant__ int g_nGrp[4]    = {1,3,1,1};
__constant__ int g_Loff[4][3] = {{1600000,0,0},{0,3216000,4848000},{3200000,0,0},{4816000,0,0}};

struct Ptrs {
    const float* x[4];
    const int*   ei[10];
    const int*   attr[4];   // for edge types 6..9
};

__device__ __forceinline__ void decode_et(int eflat, int& et, int& le) {
    if (eflat < 600000) { et = eflat / 100000; le = eflat - et * 100000; }
    else { int r = eflat - 600000; int q = r / 50000; et = 6 + q; le = r - q * 50000; }
}

// sum across the 16-lane quarter-wave group
__device__ __forceinline__ float qsum(float v) {
    v += __shfl_xor(v, 1, 64);
    v += __shfl_xor(v, 2, 64);
    v += __shfl_xor(v, 4, 64);
    v += __shfl_xor(v, 8, 64);
    return v;
}

// reduce-scatter butterfly across 16 lanes: returns element `lane` of the
// 16-vector sum over the 16-lane group's partials (static reg indices only)
__device__ __forceinline__ float reduce_scatter16(const float pr[16], int lane) {
    float v8[8];
    #pragma unroll
    for (int r=0;r<8;r++){
        float keep = (lane&8) ? pr[r+8] : pr[r];
        float give = (lane&8) ? pr[r]   : pr[r+8];
        v8[r] = keep + __shfl_xor(give, 8, 64);
    }
    float v4[4];
    #pragma unroll
    for (int r=0;r<4;r++){
        float keep = (lane&4) ? v8[r+4] : v8[r];
        float give = (lane&4) ? v8[r]   : v8[r+4];
        v4[r] = keep + __shfl_xor(give, 4, 64);
    }
    float v2[2];
    #pragma unroll
    for (int r=0;r<2;r++){
        float keep = (lane&2) ? v4[r+2] : v4[r];
        float give = (lane&2) ? v4[r]   : v4[r+2];
        v2[r] = keep + __shfl_xor(give, 2, 64);
    }
    float keep = (lane&1) ? v2[1] : v2[0];
    float give = (lane&1) ? v2[0] : v2[1];
    return keep + __shfl_xor(give, 1, 64);
}

// ---------------- K0: precompute per-edge-type tables ----------------
__global__ void k0_tables(const float* __restrict__ Wb, const float* __restrict__ A,
                          const float* __restrict__ B, const float* __restrict__ relW,
                          const float* __restrict__ behW, const float* __restrict__ a_att,
                          float* __restrict__ w0, float* __restrict__ w1,
                          float* __restrict__ cst)
{
    __shared__ float a0[128], a1[128], a2[128], a3[128];
    __shared__ float c0[128], c1[128];
    __shared__ float g0[4][16], g1[4][16];
    __shared__ float rs[10], bs[4];
    int t = threadIdx.x;
    if (t < 128) { a0[t]=a_att[t]; a1[t]=a_att[128+t]; a2[t]=a_att[256+t]; a3[t]=a_att[384+t]; }
    __syncthreads();
    if (t < 128) {
        float s0=0.f, s1=0.f;
        for (int j=0;j<128;j++){ float w=Wb[j*128+t]; s0+=w*a0[j]; s1+=w*a1[j]; }
        c0[t]=s0; c1[t]=s1;
    } else if (t < 192) {
        int q=t-128; int p=q>>4, r=q&15;
        float s0=0.f, s1=0.f;
        for (int i=0;i<128;i++){ float av=A[p*2048+i*16+r]; s0+=av*a0[i]; s1+=av*a1[i]; }
        g0[p][r]=s0; g1[p][r]=s1;
    } else if (t < 202) {
        int ri=t-192; float s=0.f;
        for (int i=0;i<128;i++) s+=relW[ri*128+i]*a2[i];
        rs[ri]=s;
    } else if (t < 206) {
        int b=t-202; float s=0.f;
        for (int i=0;i<128;i++) s+=behW[b*128+i]*a3[i];
        bs[b]=s;
    }
    __syncthreads();
    if (t < 128) {
        for (int et=0; et<10; ++et) {
            int phi=c_phi[et], beta=c_beta[et];
            if (beta >= 0) {
                float s0=c0[t], s1=c1[t];
                for (int r=0;r<16;r++){ float bv=B[beta*2048+t*16+r]; s0+=bv*g0[phi][r]; s1+=bv*g1[phi][r]; }
                w0[et*384+t]=s0;
                w0[et*384+128+t]=s0;
                w0[et*384+256+t]=s0;
                w1[et*128+t]=s1;
            } else {
                for (int o=0;o<3;o++){
                    float s0=c0[t];
                    for (int r=0;r<16;r++) s0+=B[o*2048+t*16+r]*g0[phi][r];
                    w0[et*384+o*128+t]=s0;
                }
                w1[et*128+t]=c1[t];
            }
        }
    }
    if (t == 255) {
        for (int et=0;et<10;et++){
            int beta=c_beta[et];
            if (beta>=0){ float v=rs[et]+bs[beta]; cst[et*3]=v; cst[et*3+1]=v; cst[et*3+2]=v; }
            else { for (int o=0;o<3;o++) cst[et*3+o]=rs[et]+bs[o]; }
        }
    }
}

// ---------------- ktrans: W_base^T and A^T precompute ----------------
__global__ __launch_bounds__(256) void ktrans(const float* __restrict__ Wb,
        const float* __restrict__ A, float* __restrict__ WbT, float* __restrict__ AT)
{
    int idx = blockIdx.x*256 + threadIdx.x;
    if (idx < 16384) { int i = idx>>7, j = idx&127; WbT[i*128+j] = Wb[j*128+i]; }
    int idx2 = idx - 16384;
    if (idx2 >= 0 && idx2 < 8192) {
        int p = idx2>>11, rem = idx2&2047, r = rem>>7, j = rem&127;
        AT[idx2] = A[p*2048 + j*16 + r];
    }
}

// ---------------- CSR build ----------------
__global__ __launch_bounds__(256) void khist(Ptrs P, int* __restrict__ counts)
{
    int eflat = blockIdx.x*256 + threadIdx.x;
    if (eflat >= ETOT) return;
    int et, le; decode_et(eflat, et, le);
    int dst = P.ei[et][c_E[et] + le];
    atomicAdd(&counts[c_moff[et] + dst], 1);
}

__global__ __launch_bounds__(256) void kscan1(const int* __restrict__ cnt,
                                              int* __restrict__ st, int* __restrict__ bsums)
{
    __shared__ int lds[256];
    int t = threadIdx.x, b = blockIdx.x;
    int base = b*1024 + t*4;
    int v0 = (base   < NSEG) ? cnt[base]   : 0;
    int v1 = (base+1 < NSEG) ? cnt[base+1] : 0;
    int v2 = (base+2 < NSEG) ? cnt[base+2] : 0;
    int v3 = (base+3 < NSEG) ? cnt[base+3] : 0;
    int s = v0+v1+v2+v3;
    lds[t] = s; __syncthreads();
    for (int off=1; off<256; off<<=1){
        int xv = (t>=off) ? lds[t-off] : 0;
        __syncthreads();
        lds[t] += xv;
        __syncthreads();
    }
    int incl = lds[t];
    int p = incl - s;
    if (t==255) bsums[b] = incl;
    if (base   < NSEG) st[base]   = p; p += v0;
    if (base+1 < NSEG) st[base+1] = p; p += v1;
    if (base+2 < NSEG) st[base+2] = p; p += v2;
    if (base+3 < NSEG) st[base+3] = p;
}

__global__ __launch_bounds__(256) void kscan2(int* __restrict__ bsums)
{
    __shared__ int lds[256];
    int t = threadIdx.x;
    int base = t*4;
    int v0 = (base   < NBLK) ? bsums[base]   : 0;
    int v1 = (base+1 < NBLK) ? bsums[base+1] : 0;
    int v2 = (base+2 < NBLK) ? bsums[base+2] : 0;
    int v3 = (base+3 < NBLK) ? bsums[base+3] : 0;
    int s = v0+v1+v2+v3;
    lds[t] = s; __syncthreads();
    for (int off=1; off<256; off<<=1){
        int xv = (t>=off) ? lds[t-off] : 0;
        __syncthreads();
        lds[t] += xv;
        __syncthreads();
    }
    int p = lds[t] - s;
    if (base   < NBLK) bsums[base]   = p; p += v0;
    if (base+1 < NBLK) bsums[base+1] = p; p += v1;
    if (base+2 < NBLK) bsums[base+2] = p; p += v2;
    if (base+3 < NBLK) bsums[base+3] = p;
}

__global__ __launch_bounds__(256) void kscan3(int* __restrict__ st, const int* __restrict__ bsums)
{
    int t = threadIdx.x, b = blockIdx.x;
    int add = bsums[b];
    int base = b*1024 + t*4;
    #pragma unroll
    for (int j=0;j<4;j++)
        if (base+j < NSEG) st[base+j] += add;
}

__global__ __launch_bounds__(256) void kscatter(Ptrs P, int* __restrict__ st, int* __restrict__ elist)
{
    int eflat = blockIdx.x*256 + threadIdx.x;
    if (eflat >= ETOT) return;
    int et, le; decode_et(eflat, et, le);
    int dst = P.ei[et][c_E[et] + le];
    int pos = atomicAdd(&st[c_moff[et] + dst], 1);
    elist[pos] = le;
}
// after kscatter: st[seg] == segment end; start = st[seg] - counts[seg]

// ---------------- kgather: per-dst-node online softmax + aggregate ----------------
// 16 lanes per node; writes S row (into out, as staging) and per-group L vectors.
__global__ __launch_bounds__(256) void kgather(int T, int nNodes, int rowStart, Ptrs P,
        const float* __restrict__ w0, const float* __restrict__ w1, const float* __restrict__ cst,
        const int* __restrict__ starts, const int* __restrict__ counts, const int* __restrict__ elist,
        const float* __restrict__ Bm, float* __restrict__ Sout, float* __restrict__ Lb)
{
    int t = threadIdx.x;
    int lane = t & 15, g = t >> 4;
    int n = blockIdx.x*16 + g;
    bool act = n < nNodes;

    float hdv[8] = {0,0,0,0,0,0,0,0};
    if (act) {
        const float* hp = P.x[T] + (size_t)n*D + lane*8;
        float4 a4 = *(const float4*)hp, b4 = *(const float4*)(hp+4);
        hdv[0]=a4.x; hdv[1]=a4.y; hdv[2]=a4.z; hdv[3]=a4.w;
        hdv[4]=b4.x; hdv[5]=b4.y; hdv[6]=b4.z; hdv[7]=b4.w;
    }
    float Stot[8] = {0,0,0,0,0,0,0,0};
    float Lg0=0.f, Lg1=0.f, Lg2=0.f;

    int nEt = g_nEt[T];
    if (act) {
        for (int s=0; s<nEt; ++s) {
            int et = g_ets[T][s];
            int beta = c_beta[et];
            bool structural = (beta < 0);
            const float* xs = P.x[c_srcT[et]];
            const int* ei = P.ei[et];
            const int* attr = structural ? P.attr[et-6] : (const int*)0;
            int seg = c_moff[et] + n;
            int end = starts[seg];
            int cnt = counts[seg];
            int st0 = end - cnt;
            if (cnt == 0) continue;

            // preload w0 vectors (up to 3 origins) and cst scalars
            const float* w0p = w0 + et*384 + lane*8;
            float wv0[8], wv1[8], wv2[8];
            {
                float4 a4 = *(const float4*)w0p, b4 = *(const float4*)(w0p+4);
                wv0[0]=a4.x;wv0[1]=a4.y;wv0[2]=a4.z;wv0[3]=a4.w;
                wv0[4]=b4.x;wv0[5]=b4.y;wv0[6]=b4.z;wv0[7]=b4.w;
            }
            if (structural) {
                float4 a4 = *(const float4*)(w0p+128), b4 = *(const float4*)(w0p+132);
                wv1[0]=a4.x;wv1[1]=a4.y;wv1[2]=a4.z;wv1[3]=a4.w;
                wv1[4]=b4.x;wv1[5]=b4.y;wv1[6]=b4.z;wv1[7]=b4.w;
                float4 c4 = *(const float4*)(w0p+256), d4 = *(const float4*)(w0p+260);
                wv2[0]=c4.x;wv2[1]=c4.y;wv2[2]=c4.z;wv2[3]=c4.w;
                wv2[4]=d4.x;wv2[5]=d4.y;wv2[6]=d4.z;wv2[7]=d4.w;
            } else {
                #pragma unroll
                for (int j=0;j<8;j++){ wv1[j]=wv0[j]; wv2[j]=wv0[j]; }
            }
            float cst0 = cst[et*3], cst1 = cst[et*3+1], cst2 = cst[et*3+2];

            // hd . w1[et]
            const float* w1p = w1 + et*128 + lane*8;
            float hw;
            {
                float4 a4 = *(const float4*)w1p, b4 = *(const float4*)(w1p+4);
                hw = hdv[0]*a4.x + hdv[1]*a4.y + hdv[2]*a4.z + hdv[3]*a4.w
                   + hdv[4]*b4.x + hdv[5]*b4.y + hdv[6]*b4.z + hdv[7]*b4.w;
                hw = qsum(hw);
            }

            float m = -INFINITY, ssum = 0.f, La = 0.f;
            float Sacc[8] = {0,0,0,0,0,0,0,0};

            // software pipeline: current h in (cA,cB)/oc, next indices in (le1,src1)
            int le0 = elist[st0];
            int src0 = ei[le0];
            int le1 = 0, src1 = 0;
            if (cnt > 1) { le1 = elist[st0+1]; src1 = ei[le1]; }
            const float* hp0 = xs + (size_t)src0*D + lane*8;
            float4 cA = *(const float4*)hp0, cB = *(const float4*)(hp0+4);
            int oc = 0;
            if (structural) { int a = attr[le0]; oc = min(max(a,0),2); }

            for (int k=0; k<cnt; ++k) {
                // issue next h/attr load and k+2 index chain before compute
                float4 nA = make_float4(0.f,0.f,0.f,0.f), nB = nA;
                int on = 0;
                if (k+1 < cnt) {
                    const float* hq = xs + (size_t)src1*D + lane*8;
                    nA = *(const float4*)hq; nB = *(const float4*)(hq+4);
                    if (structural) { int a = attr[le1]; on = min(max(a,0),2); }
                }
                int le2 = 0, src2 = 0;
                if (k+2 < cnt) { le2 = elist[st0+k+2]; src2 = ei[le2]; }

                int o = oc;
                float h[8] = {cA.x,cA.y,cA.z,cA.w,cB.x,cB.y,cB.z,cB.w};

                float d = 0.f;
                #pragma unroll
                for (int j=0;j<8;j++){
                    float wj = (o==0) ? wv0[j] : ((o==1) ? wv1[j] : wv2[j]);
                    d += h[j]*wj;
                }
                float csel = (o==0) ? cst0 : ((o==1) ? cst1 : cst2);
                float e = qsum(d) + hw + csel;

                float mn = fmaxf(m, e);
                float sc = expf(m - mn);
                float wg = expf(e - mn);
                ssum = ssum*sc + wg;
                #pragma unroll
                for (int j=0;j<8;j++) Sacc[j] = Sacc[j]*sc + wg*h[j];

                if (structural) {
                    float pr[16];
                    #pragma unroll
                    for (int r=0;r<16;r++) pr[r]=0.f;
                    const float* Bp = Bm + o*2048 + lane*128;
                    #pragma unroll
                    for (int j=0;j<8;j++){
                        float4 b0 = *(const float4*)(Bp + j*16);
                        float4 b1 = *(const float4*)(Bp + j*16 + 4);
                        float4 b2 = *(const float4*)(Bp + j*16 + 8);
                        float4 b3 = *(const float4*)(Bp + j*16 + 12);
                        float hv = h[j];
                        pr[0]+=hv*b0.x;  pr[1]+=hv*b0.y;  pr[2]+=hv*b0.z;  pr[3]+=hv*b0.w;
                        pr[4]+=hv*b1.x;  pr[5]+=hv*b1.y;  pr[6]+=hv*b1.z;  pr[7]+=hv*b1.w;
                        pr[8]+=hv*b2.x;  pr[9]+=hv*b2.y;  pr[10]+=hv*b2.z; pr[11]+=hv*b2.w;
                        pr[12]+=hv*b3.x; pr[13]+=hv*b3.y; pr[14]+=hv*b3.z; pr[15]+=hv*b3.w;
                    }
                    float tl = reduce_scatter16(pr, lane);
                    La = La*sc + wg*tl;
                }
                m = mn;
                cA = nA; cB = nB; oc = on;
                le1 = le2; src1 = src2;
            }

            float inv = 1.f/(ssum + 1e-16f);
            #pragma unroll
            for (int j=0;j<8;j++){ float sn = Sacc[j]*inv; Stot[j] += sn; Sacc[j] = sn; }

            float addv;
            if (structural) addv = La*inv;
            else {
                // B[beta]^T Snorm via reduce-scatter
                float pr[16];
                #pragma unroll
                for (int r=0;r<16;r++) pr[r]=0.f;
                const float* Bp = Bm + beta*2048 + lane*128;
                #pragma unroll
                for (int j=0;j<8;j++){
                    float4 b0 = *(const float4*)(Bp + j*16);
                    float4 b1 = *(const float4*)(Bp + j*16 + 4);
                    float4 b2 = *(const float4*)(Bp + j*16 + 8);
                    float4 b3 = *(const float4*)(Bp + j*16 + 12);
                    float hv = Sacc[j];
                    pr[0]+=hv*b0.x;  pr[1]+=hv*b0.y;  pr[2]+=hv*b0.z;  pr[3]+=hv*b0.w;
                    pr[4]+=hv*b1.x;  pr[5]+=hv*b1.y;  pr[6]+=hv*b1.z;  pr[7]+=hv*b1.w;
                    pr[8]+=hv*b2.x;  pr[9]+=hv*b2.y;  pr[10]+=hv*b2.z; pr[11]+=hv*b2.w;
                    pr[12]+=hv*b3.x; pr[13]+=hv*b3.y; pr[14]+=hv*b3.z; pr[15]+=hv*b3.w;
                }
                addv = reduce_scatter16(pr, lane);
            }
            int gi = g_gidx[T][s];
            if (gi==0) Lg0 += addv; else if (gi==1) Lg1 += addv; else Lg2 += addv;
        }
    }

    if (act) {
        float* Srow = Sout + (size_t)(rowStart + n)*D + lane*8;
        *(float4*)Srow     = make_float4(Stot[0],Stot[1],Stot[2],Stot[3]);
        *(float4*)(Srow+4) = make_float4(Stot[4],Stot[5],Stot[6],Stot[7]);
        int ng = g_nGrp[T];
        Lb[g_Loff[T][0] + (size_t)n*16 + lane] = Lg0;
        if (ng > 1) Lb[g_Loff[T][1] + (size_t)n*16 + lane] = Lg1;
        if (ng > 2) Lb[g_Loff[T][2] + (size_t)n*16 + lane] = Lg2;
    }
}

// ---------------- K4 v2: all-LDS tiled  agg = W_base@S + sum A[p]@L_p, LN+ELU+residual ----
// 512 threads, 128 rows/block. Columns per thread: [cg*4 .. cg*4+3] and [64+cg*4 .. 64+cg*4+3]
__global__ __launch_bounds__(512, 1) void k4_final(
        const float* __restrict__ WbT, const float* __restrict__ AT,
        const float* __restrict__ Lb, const float* __restrict__ x,
        const float* __restrict__ gamma, const float* __restrict__ lbeta,
        float* __restrict__ out, int rowStart, int nRows,
        int nPairs, int lo0, int ai0, int lo1, int ai1, int lo2, int ai2)
{
    __shared__ float st[128*132];   // S tile, stride 132
    __shared__ float wt[128*128];   // WbT tile: wt[i*128 + j]
    __shared__ float lt[128*52];    // L tile: lt[r*52 + pi*16 + k]
    int t = threadIdx.x;
    int r0 = blockIdx.x*128;

    // stage WbT (coalesced float4, conflict-free writes)
    for (int idx=t; idx<4096; idx+=512)
        *(float4*)&wt[idx*4] = *(const float4*)&WbT[idx*4];
    // stage S tile
    for (int idx=t; idx<4096; idx+=512){
        int r = idx>>5, i4 = idx&31;
        int lr = r0 + r;
        float4 v = (lr < nRows) ? *(const float4*)&out[(size_t)(rowStart+lr)*D + i4*4]
                                : make_float4(0.f,0.f,0.f,0.f);
        *(float4*)&st[r*132 + i4*4] = v;
    }
    // stage L tile (512 float4 chunks per pair)
    for (int pi=0; pi<nPairs; ++pi){
        int lo = (pi==0)?lo0:((pi==1)?lo1:lo2);
        int r = t>>2, q = t&3;
        int lr = r0 + r;
        float4 v = (lr < nRows) ? *(const float4*)&Lb[lo + (size_t)lr*16 + q*4]
                                : make_float4(0.f,0.f,0.f,0.f);
        *(float4*)&lt[r*52 + pi*16 + q*4] = v;
    }
    __syncthreads();

    int cg = t & 15, rg = t >> 4;   // rg 0..31 -> 4 rows each
    float acc[4][8];
    #pragma unroll
    for (int a=0;a<4;a++)
        #pragma unroll
        for (int c=0;c<8;c++) acc[a][c]=0.f;

    for (int i4=0; i4<32; ++i4){
        float4 sv0 = *(const float4*)&st[(rg*4+0)*132 + i4*4];
        float4 sv1 = *(const float4*)&st[(rg*4+1)*132 + i4*4];
        float4 sv2 = *(const float4*)&st[(rg*4+2)*132 + i4*4];
        float4 sv3 = *(const float4*)&st[(rg*4+3)*132 + i4*4];
        #pragma unroll
        for (int q=0;q<4;q++){
            float4 wA = *(const float4*)&wt[(i4*4+q)*128 + cg*4];
            float4 wB = *(const float4*)&wt[(i4*4+q)*128 + 64 + cg*4];
            float sq[4];
            sq[0] = (q==0)?sv0.x:(q==1)?sv0.y:(q==2)?sv0.z:sv0.w;
            sq[1] = (q==0)?sv1.x:(q==1)?sv1.y:(q==2)?sv1.z:sv1.w;
            sq[2] = (q==0)?sv2.x:(q==1)?sv2.y:(q==2)?sv2.z:sv2.w;
            sq[3] = (q==0)?sv3.x:(q==1)?sv3.y:(q==2)?sv3.z:sv3.w;
            #pragma unroll
            for (int rr=0;rr<4;rr++){
                acc[rr][0] += sq[rr]*wA.x;
                acc[rr][1] += sq[rr]*wA.y;
                acc[rr][2] += sq[rr]*wA.z;
                acc[rr][3] += sq[rr]*wA.w;
                acc[rr][4] += sq[rr]*wB.x;
                acc[rr][5] += sq[rr]*wB.y;
                acc[rr][6] += sq[rr]*wB.z;
                acc[rr][7] += sq[rr]*wB.w;
            }
        }
    }

    // low-rank: acc[rr][c] += sum_r AT[ai][r][j] * L[row][r]
    for (int pi=0; pi<nPairs; ++pi){
        int ai = (pi==0)?ai0:((pi==1)?ai1:ai2);
        const float* Ap = AT + ai*2048;
        #pragma unroll 4
        for (int r=0;r<16;++r){
            float4 aA = *(const float4*)&Ap[r*128 + cg*4];
            float4 aB = *(const float4*)&Ap[r*128 + 64 + cg*4];
            float lv[4];
            #pragma unroll
            for (int rr=0;rr<4;rr++) lv[rr] = lt[(rg*4+rr)*52 + pi*16 + r];
            #pragma unroll
            for (int rr=0;rr<4;rr++){
                acc[rr][0] += lv[rr]*aA.x;
                acc[rr][1] += lv[rr]*aA.y;
                acc[rr][2] += lv[rr]*aA.z;
                acc[rr][3] += lv[rr]*aA.w;
                acc[rr][4] += lv[rr]*aB.x;
                acc[rr][5] += lv[rr]*aB.y;
                acc[rr][6] += lv[rr]*aB.z;
                acc[rr][7] += lv[rr]*aB.w;
            }
        }
    }

    int jA = cg*4, jB = 64 + cg*4;
    float4 gA = *(const float4*)&gamma[jA], gB = *(const float4*)&gamma[jB];
    float4 bA = *(const float4*)&lbeta[jA], bB = *(const float4*)&lbeta[jB];
    float gv[8] = {gA.x,gA.y,gA.z,gA.w,gB.x,gB.y,gB.z,gB.w};
    float bv[8] = {bA.x,bA.y,bA.z,bA.w,bB.x,bB.y,bB.z,bB.w};

    #pragma unroll
    for (int rr=0;rr<4;rr++){
        int lr = r0 + rg*4 + rr;
        float lsum=0.f, lsq=0.f;
        #pragma unroll
        for (int c=0;c<8;c++){ lsum += acc[rr][c]; lsq += acc[rr][c]*acc[rr][c]; }
        #pragma unroll
        for (int mm=1; mm<16; mm<<=1){ lsum += __shfl_xor(lsum,mm,64); lsq += __shfl_xor(lsq,mm,64); }
        if (lr >= nRows) continue;
        float mu = lsum*(1.f/128.f);
        float var = lsq*(1.f/128.f) - mu*mu;
        float rstd = rsqrtf(var + 1e-5f);
        const float* xr = x + (size_t)lr*D;
        float4 xA = *(const float4*)(xr+jA), xB = *(const float4*)(xr+jB);
        float xv[8] = {xA.x,xA.y,xA.z,xA.w,xB.x,xB.y,xB.z,xB.w};
        float ov[8];
        #pragma unroll
        for (int c=0;c<8;c++){
            float hn = (acc[rr][c]-mu)*rstd*gv[c] + bv[c];
            float z = hn + xv[c];
            ov[c] = z > 0.f ? z : expm1f(z);
        }
        float* orow = out + (size_t)(rowStart+lr)*D;
        *(float4*)(orow+jA) = make_float4(ov[0],ov[1],ov[2],ov[3]);
        *(float4*)(orow+jB) = make_float4(ov[4],ov[5],ov[6],ov[7]);
    }
}

extern "C" void kernel_launch(void* const* d_in, const int* in_sizes, int n_in,
                              void* d_out, int out_size, void* d_ws, size_t ws_size,
                              hipStream_t stream)
{
    (void)in_sizes; (void)n_in; (void)out_size; (void)ws_size;
    Ptrs P;
    P.x[0] = (const float*)d_in[0];   // x_user
    P.x[1] = (const float*)d_in[1];   // x_product
    P.x[2] = (const float*)d_in[2];   // x_category
    P.x[3] = (const float*)d_in[3];   // x_brand
    P.ei[0] = (const int*)d_in[4];    // view
    P.ei[1] = (const int*)d_in[5];    // cart
    P.ei[2] = (const int*)d_in[6];    // purchase
    P.ei[3] = (const int*)d_in[7];    // rev_view
    P.ei[4] = (const int*)d_in[8];    // rev_cart
    P.ei[5] = (const int*)d_in[9];    // rev_purchase
    P.ei[6] = (const int*)d_in[10];   // belongs_to
    P.attr[0] = (const int*)d_in[11];
    P.ei[7] = (const int*)d_in[12];   // contains
    P.attr[1] = (const int*)d_in[13];
    P.ei[8] = (const int*)d_in[14];   // producedBy
    P.attr[2] = (const int*)d_in[15];
    P.ei[9] = (const int*)d_in[16];   // brands
    P.attr[3] = (const int*)d_in[17];
    const float* Wb    = (const float*)d_in[18];
    const float* A     = (const float*)d_in[19];
    const float* B     = (const float*)d_in[20];
    const float* relW  = (const float*)d_in[21];
    const float* behW  = (const float*)d_in[22];
    const float* a_att = (const float*)d_in[23];
    const float* gamma = (const float*)d_in[24];
    const float* lbeta = (const float*)d_in[25];
    float* wsf = (float*)d_ws;
    float* out = (float*)d_out;

    int* ip     = (int*)(wsf + OFF_INT);
    int* counts = ip;
    int* starts = ip + 803000;
    int* elist  = ip + 1606000;
    int* bsums  = (int*)wsf;          // overlays L region, used only pre-gather

    hipMemsetAsync(counts, 0, (size_t)NSEG*sizeof(int), stream);

    k0_tables<<<1, 256, 0, stream>>>(Wb, A, B, relW, behW, a_att,
                                     wsf+OFF_W0, wsf+OFF_W1, wsf+OFF_CST);
    ktrans<<<96, 256, 0, stream>>>(Wb, A, wsf+OFF_WT, wsf+OFF_AT);
    khist<<<3125, 256, 0, stream>>>(P, counts);
    kscan1<<<NBLK, 256, 0, stream>>>(counts, starts, bsums);
    kscan2<<<1, 256, 0, stream>>>(bsums);
    kscan3<<<NBLK, 256, 0, stream>>>(starts, bsums);
    kscatter<<<3125, 256, 0, stream>>>(P, starts, elist);

    kgather<<<(NU+15)/16, 256, 0, stream>>>(0, NU, 0,      P, wsf+OFF_W0, wsf+OFF_W1, wsf+OFF_CST,
                                            starts, counts, elist, B, out, wsf+OFF_L);
    kgather<<<(NP+15)/16, 256, 0, stream>>>(1, NP, 100000, P, wsf+OFF_W0, wsf+OFF_W1, wsf+OFF_CST,
                                            starts, counts, elist, B, out, wsf+OFF_L);
    kgather<<<(NC+15)/16, 256, 0, stream>>>(2, NC, 200000, P, wsf+OFF_W0, wsf+OFF_W1, wsf+OFF_CST,
                                            starts, counts, elist, B, out, wsf+OFF_L);
    kgather<<<(NB+15)/16, 256, 0, stream>>>(3, NB, 201000, P, wsf+OFF_W0, wsf+OFF_W1, wsf+OFF_CST,
                                            starts, counts, elist, B, out, wsf+OFF_L);

    k4_final<<<(NU+127)/128, 512, 0, stream>>>(wsf+OFF_WT, wsf+OFF_AT, wsf+OFF_L, P.x[0], gamma, lbeta, out,
                                               0,      NU, 1, 1600000,1, 0,0, 0,0);
    k4_final<<<(NP+127)/128, 512, 0, stream>>>(wsf+OFF_WT, wsf+OFF_AT, wsf+OFF_L, P.x[1], gamma, lbeta, out,
                                               100000, NP, 3, 0,0, 3216000,2, 4848000,3);
    k4_final<<<(NC+127)/128, 512, 0, stream>>>(wsf+OFF_WT, wsf+OFF_AT, wsf+OFF_L, P.x[2], gamma, lbeta, out,
                                               200000, NC, 1, 3200000,1, 0,0, 0,0);
    k4_final<<<(NB+127)/128, 512, 0, stream>>>(wsf+OFF_WT, wsf+OFF_AT, wsf+OFF_L, P.x[3], gamma, lbeta, out,
                                               201000, NB, 1, 4816000,1, 0,0, 0,0);
}

// Round 4
// 1285.319 us; speedup vs baseline: 3.1566x; 1.1526x over previous
//
#include <hip/hip_runtime.h>
#include <hip/hip_bf16.h>
#include <math.h>

#define D 128

// problem sizes (fixed by reference)
#define NU 100000
#define NP 100000
#define NC 1000
#define NB 2000
#define NTOT 203000
#define EB 100000
#define ES 50000
#define ETOT 800000
#define NSEG 803000
#define NBLK 785          // ceil(NSEG/1024)

// ws layout (float offsets)
#define OFF_L    0            // 6448000 floats: low-rank accumulators
#define OFF_W0   6448000      // 10*3*128
#define OFF_BS   6451840      // 16 (bs[4])
#define OFF_ECSR 6451856      // 800000 floats: e then alpha, CSR order
#define OFF_WT   7251856      // 16384 floats: W_base^T
#define OFF_AT   7268240      // 8192 floats: A^T per phi
#define OFF_INT  7276432      // int region
// ints relative to (int*)(wsf+OFF_INT):
//   counts @ 0        (803000)
//   starts @ 803000   (803000)  -- after kscatter: segment END
//   srco   @ 1606000  (800000)  -- src | o<<17 | et<<19, CSR order
//   ticket @ 2406000  (1)
// bsums (785 ints) overlays OFF_L (only used before kagg rewrites L)

// per-edge-type metadata
__constant__ int c_srcT[10]   = {0,0,0,1,1,1,1,2,1,3};
__constant__ int c_phi [10]   = {0,0,0,1,1,1,1,2,1,3};
__constant__ int c_beta[10]   = {0,1,2,0,1,2,-1,-1,-1,-1};
__constant__ int c_E   [10]   = {EB,EB,EB,EB,EB,EB,ES,ES,ES,ES};
__constant__ int c_moff[10]   = {0,100000,200000,300000,400000,500000,600000,601000,701000,703000};

// per-dst-type gather config
__constant__ int g_nEt[4]     = {3,5,1,1};
__constant__ int g_ets[4][5]  = {{3,4,5,0,0},{0,1,2,7,9},{6,0,0,0,0},{8,0,0,0,0}};
__constant__ int g_gidx[4][5] = {{0,0,0,0,0},{0,0,0,1,2},{0,0,0,0,0},{0,0,0,0,0}};
__constant__ int g_nGrp[4]    = {1,3,1,1};
__constant__ int g_Loff[4][3] = {{1600000,0,0},{0,3216000,4848000},{3200000,0,0},{4816000,0,0}};

struct Ptrs {
    const float* x[4];
    const int*   ei[10];
    const int*   attr[4];   // for edge types 6..9
};

__device__ __forceinline__ void decode_et(int eflat, int& et, int& le) {
    if (eflat < 600000) { et = eflat / 100000; le = eflat - et * 100000; }
    else { int r = eflat - 600000; int q = r / 50000; et = 6 + q; le = r - q * 50000; }
}

// sum across the 16-lane quarter-wave group
__device__ __forceinline__ float qsum(float v) {
    v += __shfl_xor(v, 1, 64);
    v += __shfl_xor(v, 2, 64);
    v += __shfl_xor(v, 4, 64);
    v += __shfl_xor(v, 8, 64);
    return v;
}

// reduce-scatter butterfly across 16 lanes: returns element `lane` of the
// 16-vector sum over the 16-lane group's partials (static reg indices only)
__device__ __forceinline__ float reduce_scatter16(const float pr[16], int lane) {
    float v8[8];
    #pragma unroll
    for (int r=0;r<8;r++){
        float keep = (lane&8) ? pr[r+8] : pr[r];
        float give = (lane&8) ? pr[r]   : pr[r+8];
        v8[r] = keep + __shfl_xor(give, 8, 64);
    }
    float v4[4];
    #pragma unroll
    for (int r=0;r<4;r++){
        float keep = (lane&4) ? v8[r+4] : v8[r];
        float give = (lane&4) ? v8[r]   : v8[r+4];
        v4[r] = keep + __shfl_xor(give, 4, 64);
    }
    float v2[2];
    #pragma unroll
    for (int r=0;r<2;r++){
        float keep = (lane&2) ? v2[0]*0.f + ((lane&2)?v4[r+2]:v4[r]) : v4[r];
        (void)keep;
        float kp = (lane&2) ? v4[r+2] : v4[r];
        float gv = (lane&2) ? v4[r]   : v4[r+2];
        v2[r] = kp + __shfl_xor(gv, 2, 64);
    }
    float kp = (lane&1) ? v2[1] : v2[0];
    float gv = (lane&1) ? v2[0] : v2[1];
    return kp + __shfl_xor(gv, 1, 64);
}

// B^T S partial accumulation: lane's 8 rows of B[sel], into pr[0..15]
__device__ __forceinline__ void accum_bT(float pr[16], const float S[8], const float* __restrict__ Bp)
{
    #pragma unroll
    for (int j=0;j<8;j++){
        float4 b0 = *(const float4*)(Bp + j*16);
        float4 b1 = *(const float4*)(Bp + j*16 + 4);
        float4 b2 = *(const float4*)(Bp + j*16 + 8);
        float4 b3 = *(const float4*)(Bp + j*16 + 12);
        float hv = S[j];
        pr[0]+=hv*b0.x;  pr[1]+=hv*b0.y;  pr[2]+=hv*b0.z;  pr[3]+=hv*b0.w;
        pr[4]+=hv*b1.x;  pr[5]+=hv*b1.y;  pr[6]+=hv*b1.z;  pr[7]+=hv*b1.w;
        pr[8]+=hv*b2.x;  pr[9]+=hv*b2.y;  pr[10]+=hv*b2.z; pr[11]+=hv*b2.w;
        pr[12]+=hv*b3.x; pr[13]+=hv*b3.y; pr[14]+=hv*b3.z; pr[15]+=hv*b3.w;
    }
}

// ---------------- K0: w0 tables + bs (softmax-invariant terms dropped) ----------------
__global__ void k0_tables(const float* __restrict__ Wb, const float* __restrict__ A,
                          const float* __restrict__ B, const float* __restrict__ behW,
                          const float* __restrict__ a_att,
                          float* __restrict__ w0, float* __restrict__ bs_out)
{
    __shared__ float a0[128];
    __shared__ float c0[128];
    __shared__ float g0[4][16];
    int t = threadIdx.x;
    if (t < 128) a0[t] = a_att[t];
    __syncthreads();
    if (t < 128) {
        float s0=0.f;
        for (int j=0;j<128;j++) s0 += Wb[j*128+t]*a0[j];
        c0[t]=s0;
    } else if (t < 192) {
        int q=t-128, p=q>>4, r=q&15;
        float s0=0.f;
        for (int i=0;i<128;i++) s0 += A[p*2048+i*16+r]*a0[i];
        g0[p][r]=s0;
    } else if (t < 196) {
        int b=t-192; float s=0.f;
        for (int i=0;i<128;i++) s += behW[b*128+i]*a_att[384+i];
        bs_out[b]=s;
    }
    __syncthreads();
    if (t < 128) {
        for (int et=0; et<10; ++et) {
            int phi=c_phi[et], beta=c_beta[et];
            if (beta >= 0) {
                float s0=c0[t];
                for (int r=0;r<16;r++) s0 += B[beta*2048+t*16+r]*g0[phi][r];
                w0[et*384+t]=s0; w0[et*384+128+t]=s0; w0[et*384+256+t]=s0;
            } else {
                for (int o=0;o<3;o++){
                    float s0=c0[t];
                    for (int r=0;r<16;r++) s0 += B[o*2048+t*16+r]*g0[phi][r];
                    w0[et*384+o*128+t]=s0;
                }
            }
        }
    }
}

// ---------------- ktrans: W_base^T and A^T precompute ----------------
__global__ __launch_bounds__(256) void ktrans(const float* __restrict__ Wb,
        const float* __restrict__ A, float* __restrict__ WbT, float* __restrict__ AT)
{
    int idx = blockIdx.x*256 + threadIdx.x;
    if (idx < 16384) { int i = idx>>7, j = idx&127; WbT[i*128+j] = Wb[j*128+i]; }
    int idx2 = idx - 16384;
    if (idx2 >= 0 && idx2 < 8192) {
        int p = idx2>>11, rem = idx2&2047, r = rem>>7, j = rem&127;
        AT[idx2] = A[p*2048 + j*16 + r];
    }
}

// ---------------- CSR build ----------------
__global__ __launch_bounds__(256) void khist(Ptrs P, int* __restrict__ counts)
{
    int eflat = blockIdx.x*256 + threadIdx.x;
    if (eflat >= ETOT) return;
    int et, le; decode_et(eflat, et, le);
    int dst = P.ei[et][c_E[et] + le];
    atomicAdd(&counts[c_moff[et] + dst], 1);
}

__global__ __launch_bounds__(256) void kscan1(const int* __restrict__ cnt,
                                              int* __restrict__ st, int* __restrict__ bsums)
{
    __shared__ int lds[256];
    int t = threadIdx.x, b = blockIdx.x;
    int base = b*1024 + t*4;
    int v0 = (base   < NSEG) ? cnt[base]   : 0;
    int v1 = (base+1 < NSEG) ? cnt[base+1] : 0;
    int v2 = (base+2 < NSEG) ? cnt[base+2] : 0;
    int v3 = (base+3 < NSEG) ? cnt[base+3] : 0;
    int s = v0+v1+v2+v3;
    lds[t] = s; __syncthreads();
    for (int off=1; off<256; off<<=1){
        int xv = (t>=off) ? lds[t-off] : 0;
        __syncthreads();
        lds[t] += xv;
        __syncthreads();
    }
    int incl = lds[t];
    int p = incl - s;
    if (t==255) bsums[b] = incl;
    if (base   < NSEG) st[base]   = p; p += v0;
    if (base+1 < NSEG) st[base+1] = p; p += v1;
    if (base+2 < NSEG) st[base+2] = p; p += v2;
    if (base+3 < NSEG) st[base+3] = p;
}

__global__ __launch_bounds__(256) void kscan2(int* __restrict__ bsums)
{
    __shared__ int lds[256];
    int t = threadIdx.x;
    int base = t*4;
    int v0 = (base   < NBLK) ? bsums[base]   : 0;
    int v1 = (base+1 < NBLK) ? bsums[base+1] : 0;
    int v2 = (base+2 < NBLK) ? bsums[base+2] : 0;
    int v3 = (base+3 < NBLK) ? bsums[base+3] : 0;
    int s = v0+v1+v2+v3;
    lds[t] = s; __syncthreads();
    for (int off=1; off<256; off<<=1){
        int xv = (t>=off) ? lds[t-off] : 0;
        __syncthreads();
        lds[t] += xv;
        __syncthreads();
    }
    int p = lds[t] - s;
    if (base   < NBLK) bsums[base]   = p; p += v0;
    if (base+1 < NBLK) bsums[base+1] = p; p += v1;
    if (base+2 < NBLK) bsums[base+2] = p; p += v2;
    if (base+3 < NBLK) bsums[base+3] = p;
}

__global__ __launch_bounds__(256) void kscan3(int* __restrict__ st, const int* __restrict__ bsums)
{
    int t = threadIdx.x, b = blockIdx.x;
    int add = bsums[b];
    int base = b*1024 + t*4;
    #pragma unroll
    for (int j=0;j<4;j++)
        if (base+j < NSEG) st[base+j] += add;
}

__global__ __launch_bounds__(256) void kscatter(Ptrs P, int* __restrict__ st, int* __restrict__ srco)
{
    int eflat = blockIdx.x*256 + threadIdx.x;
    if (eflat >= ETOT) return;
    int et, le; decode_et(eflat, et, le);
    const int* ei = P.ei[et];
    int E = c_E[et];
    int src = ei[le], dst = ei[E+le];
    int o = 0;
    if (et >= 6) { int a = P.attr[et-6][le]; o = min(max(a,0),2); }
    int pos = atomicAdd(&st[c_moff[et] + dst], 1);
    srco[pos] = src | (o<<17) | (et<<19);
}
// after kscatter: st[seg] == segment end; start = st[seg] - counts[seg]

// ---------------- kedge: edge-parallel logit (16 lanes/edge, no serial chain) --------
__global__ __launch_bounds__(256) void kedge(Ptrs P, const float* __restrict__ w0,
        const float* __restrict__ bs, const int* __restrict__ srco,
        float* __restrict__ ecsr)
{
    int tid = blockIdx.x*256 + threadIdx.x;
    int p = tid >> 4, lane = tid & 15;
    if (p >= ETOT) return;
    int sv = srco[p];
    int src = sv & 0x1FFFF, o = (sv>>17)&3, et = sv>>19;
    const float* hp = P.x[c_srcT[et]] + (size_t)src*D + lane*8;
    const float* wp = w0 + et*384 + o*128 + lane*8;
    float4 hA = *(const float4*)hp, hB = *(const float4*)(hp+4);
    float4 wA = *(const float4*)wp, wB = *(const float4*)(wp+4);
    float d = hA.x*wA.x + hA.y*wA.y + hA.z*wA.z + hA.w*wA.w
            + hB.x*wB.x + hB.y*wB.y + hB.z*wB.z + hB.w*wB.w;
    d = qsum(d);
    if (lane == 0) ecsr[p] = d + ((et>=6) ? bs[o] : 0.f);
}

// ---------------- kseg: per-segment softmax normalize (e -> alpha, in place) ---------
__global__ __launch_bounds__(256) void kseg(const int* __restrict__ starts,
        const int* __restrict__ counts, float* __restrict__ ecsr)
{
    int seg = blockIdx.x*256 + threadIdx.x;
    if (seg >= NSEG) return;
    int cnt = counts[seg];
    if (cnt == 0) return;
    int end = starts[seg], st0 = end - cnt;
    float m = -INFINITY;
    for (int p=st0; p<end; ++p) m = fmaxf(m, ecsr[p]);
    float ss = 0.f;
    for (int p=st0; p<end; ++p) ss += __expf(ecsr[p]-m);
    float inv = 1.f/(ss + 1e-16f);
    for (int p=st0; p<end; ++p) ecsr[p] = __expf(ecsr[p]-m)*inv;
}

// ---------------- kagg: node-parallel weighted aggregation, dynamic work queue -------
__global__ __launch_bounds__(256) void kagg(Ptrs P,
        const int* __restrict__ starts, const int* __restrict__ counts,
        const int* __restrict__ srco, const float* __restrict__ alpha,
        const float* __restrict__ Bm, float* __restrict__ Sout,
        float* __restrict__ Lb, int* __restrict__ ticket)
{
    int t = threadIdx.x;
    int lane = t & 15;
    int srcl = (t & 63) & 48;   // lane0 of this 16-lane group within the wave
    for (;;) {
        int nid = 0;
        if (lane == 0) nid = atomicAdd(ticket, 1);
        nid = __shfl(nid, srcl, 64);
        if (nid >= NTOT) return;

        int T, n0;
        if (nid < NU) { T=0; n0=nid; }
        else if (nid < 200000) { T=1; n0=nid-100000; }
        else if (nid < 201000) { T=2; n0=nid-200000; }
        else { T=3; n0=nid-201000; }

        float Stot[8] = {0,0,0,0,0,0,0,0};
        float Lg0=0.f, Lg1=0.f, Lg2=0.f;
        int nEt = g_nEt[T];
        for (int s=0; s<nEt; ++s) {
            int et = g_ets[T][s];
            int seg = c_moff[et] + n0;
            int cnt = counts[seg];
            if (cnt == 0) continue;
            int end = starts[seg], st0 = end - cnt;
            bool structural = (et >= 6);
            const float* xs = P.x[c_srcT[et]];

            float SA[8]={0,0,0,0,0,0,0,0}, SB[8]={0,0,0,0,0,0,0,0}, SC[8]={0,0,0,0,0,0,0,0};
            int fa=0, fb=0, fc=0;

            // depth-2 software pipeline over the segment's edges
            float a0v=0.f, a1v=0.f; int o0=0, o1=0;
            float4 h0A, h0B, h1A, h1B;
            {
                a0v = alpha[st0]; int sv = srco[st0];
                int sr = sv & 0x1FFFF; o0 = (sv>>17)&3;
                const float* q = xs + (size_t)sr*D + lane*8;
                h0A = *(const float4*)q; h0B = *(const float4*)(q+4);
            }
            if (cnt > 1) {
                a1v = alpha[st0+1]; int sv = srco[st0+1];
                int sr = sv & 0x1FFFF; o1 = (sv>>17)&3;
                const float* q = xs + (size_t)sr*D + lane*8;
                h1A = *(const float4*)q; h1B = *(const float4*)(q+4);
            } else { h1A = make_float4(0.f,0.f,0.f,0.f); h1B = h1A; }

            for (int k=0; k<cnt; ++k) {
                float4 h2A = make_float4(0.f,0.f,0.f,0.f), h2B = h2A;
                float a2v = 0.f; int o2 = 0;
                if (k+2 < cnt) {
                    a2v = alpha[st0+k+2]; int sv = srco[st0+k+2];
                    int sr = sv & 0x1FFFF; o2 = (sv>>17)&3;
                    const float* q = xs + (size_t)sr*D + lane*8;
                    h2A = *(const float4*)q; h2B = *(const float4*)(q+4);
                }
                float h[8] = {h0A.x,h0A.y,h0A.z,h0A.w,h0B.x,h0B.y,h0B.z,h0B.w};
                if (o0 == 0) {
                    #pragma unroll
                    for (int j=0;j<8;j++) SA[j] += a0v*h[j];
                    fa = 1;
                } else if (o0 == 1) {
                    #pragma unroll
                    for (int j=0;j<8;j++) SB[j] += a0v*h[j];
                    fb = 1;
                } else {
                    #pragma unroll
                    for (int j=0;j<8;j++) SC[j] += a0v*h[j];
                    fc = 1;
                }
                h0A=h1A; h0B=h1B; a0v=a1v; o0=o1;
                h1A=h2A; h1B=h2B; a1v=a2v; o1=o2;
            }

            float pr[16];
            #pragma unroll
            for (int r=0;r<16;r++) pr[r]=0.f;
            if (structural) {
                #pragma unroll
                for (int j=0;j<8;j++) Stot[j] += SA[j]+SB[j]+SC[j];
                if (fa) accum_bT(pr, SA, Bm + 0*2048 + lane*128);
                if (fb) accum_bT(pr, SB, Bm + 1*2048 + lane*128);
                if (fc) accum_bT(pr, SC, Bm + 2*2048 + lane*128);
            } else {
                #pragma unroll
                for (int j=0;j<8;j++) Stot[j] += SA[j];
                int beta = c_beta[et];
                accum_bT(pr, SA, Bm + beta*2048 + lane*128);
            }
            float addv = reduce_scatter16(pr, lane);
            int gi = g_gidx[T][s];
            if (gi==0) Lg0 += addv; else if (gi==1) Lg1 += addv; else Lg2 += addv;
        }

        float* Srow = Sout + (size_t)nid*D + lane*8;
        *(float4*)Srow     = make_float4(Stot[0],Stot[1],Stot[2],Stot[3]);
        *(float4*)(Srow+4) = make_float4(Stot[4],Stot[5],Stot[6],Stot[7]);
        int ng = g_nGrp[T];
        Lb[g_Loff[T][0] + (size_t)n0*16 + lane] = Lg0;
        if (ng > 1) Lb[g_Loff[T][1] + (size_t)n0*16 + lane] = Lg1;
        if (ng > 2) Lb[g_Loff[T][2] + (size_t)n0*16 + lane] = Lg2;
    }
}

// ---------------- K4: all-LDS tiled  agg = W_base@S + sum A[p]@L_p, LN+ELU+residual ----
__global__ __launch_bounds__(512, 1) void k4_final(
        const float* __restrict__ WbT, const float* __restrict__ AT,
        const float* __restrict__ Lb, const float* __restrict__ x,
        const float* __restrict__ gamma, const float* __restrict__ lbeta,
        float* __restrict__ out, int rowStart, int nRows,
        int nPairs, int lo0, int ai0, int lo1, int ai1, int lo2, int ai2)
{
    __shared__ float st[128*132];   // S tile, stride 132
    __shared__ float wt[128*128];   // WbT tile: wt[i*128 + j]
    __shared__ float lt[128*52];    // L tile: lt[r*52 + pi*16 + k]
    int t = threadIdx.x;
    int r0 = blockIdx.x*128;

    for (int idx=t; idx<4096; idx+=512)
        *(float4*)&wt[idx*4] = *(const float4*)&WbT[idx*4];
    for (int idx=t; idx<4096; idx+=512){
        int r = idx>>5, i4 = idx&31;
        int lr = r0 + r;
        float4 v = (lr < nRows) ? *(const float4*)&out[(size_t)(rowStart+lr)*D + i4*4]
                                : make_float4(0.f,0.f,0.f,0.f);
        *(float4*)&st[r*132 + i4*4] = v;
    }
    for (int pi=0; pi<nPairs; ++pi){
        int lo = (pi==0)?lo0:((pi==1)?lo1:lo2);
        int r = t>>2, q = t&3;
        int lr = r0 + r;
        float4 v = (lr < nRows) ? *(const float4*)&Lb[lo + (size_t)lr*16 + q*4]
                                : make_float4(0.f,0.f,0.f,0.f);
        *(float4*)&lt[r*52 + pi*16 + q*4] = v;
    }
    __syncthreads();

    int cg = t & 15, rg = t >> 4;
    float acc[4][8];
    #pragma unroll
    for (int a=0;a<4;a++)
        #pragma unroll
        for (int c=0;c<8;c++) acc[a][c]=0.f;

    for (int i4=0; i4<32; ++i4){
        float4 sv0 = *(const float4*)&st[(rg*4+0)*132 + i4*4];
        float4 sv1 = *(const float4*)&st[(rg*4+1)*132 + i4*4];
        float4 sv2 = *(const float4*)&st[(rg*4+2)*132 + i4*4];
        float4 sv3 = *(const float4*)&st[(rg*4+3)*132 + i4*4];
        #pragma unroll
        for (int q=0;q<4;q++){
            float4 wA = *(const float4*)&wt[(i4*4+q)*128 + cg*4];
            float4 wB = *(const float4*)&wt[(i4*4+q)*128 + 64 + cg*4];
            float sq[4];
            sq[0] = (q==0)?sv0.x:(q==1)?sv0.y:(q==2)?sv0.z:sv0.w;
            sq[1] = (q==0)?sv1.x:(q==1)?sv1.y:(q==2)?sv1.z:sv1.w;
            sq[2] = (q==0)?sv2.x:(q==1)?sv2.y:(q==2)?sv2.z:sv2.w;
            sq[3] = (q==0)?sv3.x:(q==1)?sv3.y:(q==2)?sv3.z:sv3.w;
            #pragma unroll
            for (int rr=0;rr<4;rr++){
                acc[rr][0] += sq[rr]*wA.x;
                acc[rr][1] += sq[rr]*wA.y;
                acc[rr][2] += sq[rr]*wA.z;
                acc[rr][3] += sq[rr]*wA.w;
                acc[rr][4] += sq[rr]*wB.x;
                acc[rr][5] += sq[rr]*wB.y;
                acc[rr][6] += sq[rr]*wB.z;
                acc[rr][7] += sq[rr]*wB.w;
            }
        }
    }

    for (int pi=0; pi<nPairs; ++pi){
        int ai = (pi==0)?ai0:((pi==1)?ai1:ai2);
        const float* Ap = AT + ai*2048;
        #pragma unroll 4
        for (int r=0;r<16;++r){
            float4 aA = *(const float4*)&Ap[r*128 + cg*4];
            float4 aB = *(const float4*)&Ap[r*128 + 64 + cg*4];
            float lv[4];
            #pragma unroll
            for (int rr=0;rr<4;rr++) lv[rr] = lt[(rg*4+rr)*52 + pi*16 + r];
            #pragma unroll
            for (int rr=0;rr<4;rr++){
                acc[rr][0] += lv[rr]*aA.x;
                acc[rr][1] += lv[rr]*aA.y;
                acc[rr][2] += lv[rr]*aA.z;
                acc[rr][3] += lv[rr]*aA.w;
                acc[rr][4] += lv[rr]*aB.x;
                acc[rr][5] += lv[rr]*aB.y;
                acc[rr][6] += lv[rr]*aB.z;
                acc[rr][7] += lv[rr]*aB.w;
            }
        }
    }

    int jA = cg*4, jB = 64 + cg*4;
    float4 gA = *(const float4*)&gamma[jA], gB = *(const float4*)&gamma[jB];
    float4 bA = *(const float4*)&lbeta[jA], bB = *(const float4*)&lbeta[jB];
    float gv[8] = {gA.x,gA.y,gA.z,gA.w,gB.x,gB.y,gB.z,gB.w};
    float bv[8] = {bA.x,bA.y,bA.z,bA.w,bB.x,bB.y,bB.z,bB.w};

    #pragma unroll
    for (int rr=0;rr<4;rr++){
        int lr = r0 + rg*4 + rr;
        float lsum=0.f, lsq=0.f;
        #pragma unroll
        for (int c=0;c<8;c++){ lsum += acc[rr][c]; lsq += acc[rr][c]*acc[rr][c]; }
        #pragma unroll
        for (int mm=1; mm<16; mm<<=1){ lsum += __shfl_xor(lsum,mm,64); lsq += __shfl_xor(lsq,mm,64); }
        if (lr >= nRows) continue;
        float mu = lsum*(1.f/128.f);
        float var = lsq*(1.f/128.f) - mu*mu;
        float rstd = rsqrtf(var + 1e-5f);
        const float* xr = x + (size_t)lr*D;
        float4 xA = *(const float4*)(xr+jA), xB = *(const float4*)(xr+jB);
        float xv[8] = {xA.x,xA.y,xA.z,xA.w,xB.x,xB.y,xB.z,xB.w};
        float ov[8];
        #pragma unroll
        for (int c=0;c<8;c++){
            float hn = (acc[rr][c]-mu)*rstd*gv[c] + bv[c];
            float z = hn + xv[c];
            ov[c] = z > 0.f ? z : expm1f(z);
        }
        float* orow = out + (size_t)(rowStart+lr)*D;
        *(float4*)(orow+jA) = make_float4(ov[0],ov[1],ov[2],ov[3]);
        *(float4*)(orow+jB) = make_float4(ov[4],ov[5],ov[6],ov[7]);
    }
}

extern "C" void kernel_launch(void* const* d_in, const int* in_sizes, int n_in,
                              void* d_out, int out_size, void* d_ws, size_t ws_size,
                              hipStream_t stream)
{
    (void)in_sizes; (void)n_in; (void)out_size; (void)ws_size;
    Ptrs P;
    P.x[0] = (const float*)d_in[0];   // x_user
    P.x[1] = (const float*)d_in[1];   // x_product
    P.x[2] = (const float*)d_in[2];   // x_category
    P.x[3] = (const float*)d_in[3];   // x_brand
    P.ei[0] = (const int*)d_in[4];    // view
    P.ei[1] = (const int*)d_in[5];    // cart
    P.ei[2] = (const int*)d_in[6];    // purchase
    P.ei[3] = (const int*)d_in[7];    // rev_view
    P.ei[4] = (const int*)d_in[8];    // rev_cart
    P.ei[5] = (const int*)d_in[9];    // rev_purchase
    P.ei[6] = (const int*)d_in[10];   // belongs_to
    P.attr[0] = (const int*)d_in[11];
    P.ei[7] = (const int*)d_in[12];   // contains
    P.attr[1] = (const int*)d_in[13];
    P.ei[8] = (const int*)d_in[14];   // producedBy
    P.attr[2] = (const int*)d_in[15];
    P.ei[9] = (const int*)d_in[16];   // brands
    P.attr[3] = (const int*)d_in[17];
    const float* Wb    = (const float*)d_in[18];
    const float* A     = (const float*)d_in[19];
    const float* B     = (const float*)d_in[20];
    const float* behW  = (const float*)d_in[22];
    const float* a_att = (const float*)d_in[23];
    const float* gamma = (const float*)d_in[24];
    const float* lbeta = (const float*)d_in[25];
    float* wsf = (float*)d_ws;
    float* out = (float*)d_out;

    int* ip     = (int*)(wsf + OFF_INT);
    int* counts = ip;
    int* starts = ip + 803000;
    int* srco   = ip + 1606000;
    int* ticket = ip + 2406000;
    int* bsums  = (int*)wsf;          // overlays L region, used only pre-kagg

    hipMemsetAsync(counts, 0, (size_t)NSEG*sizeof(int), stream);
    hipMemsetAsync(ticket, 0, sizeof(int), stream);

    k0_tables<<<1, 256, 0, stream>>>(Wb, A, B, behW, a_att, wsf+OFF_W0, wsf+OFF_BS);
    ktrans<<<96, 256, 0, stream>>>(Wb, A, wsf+OFF_WT, wsf+OFF_AT);
    khist<<<3125, 256, 0, stream>>>(P, counts);
    kscan1<<<NBLK, 256, 0, stream>>>(counts, starts, bsums);
    kscan2<<<1, 256, 0, stream>>>(bsums);
    kscan3<<<NBLK, 256, 0, stream>>>(starts, bsums);
    kscatter<<<3125, 256, 0, stream>>>(P, starts, srco);

    kedge<<<50000, 256, 0, stream>>>(P, wsf+OFF_W0, wsf+OFF_BS, srco, wsf+OFF_ECSR);
    kseg<<<(NSEG+255)/256, 256, 0, stream>>>(starts, counts, wsf+OFF_ECSR);
    kagg<<<1024, 256, 0, stream>>>(P, starts, counts, srco, wsf+OFF_ECSR, B,
                                   out, wsf+OFF_L, ticket);

    k4_final<<<(NU+127)/128, 512, 0, stream>>>(wsf+OFF_WT, wsf+OFF_AT, wsf+OFF_L, P.x[0], gamma, lbeta, out,
                                               0,      NU, 1, 1600000,1, 0,0, 0,0);
    k4_final<<<(NP+127)/128, 512, 0, stream>>>(wsf+OFF_WT, wsf+OFF_AT, wsf+OFF_L, P.x[1], gamma, lbeta, out,
                                               100000, NP, 3, 0,0, 3216000,2, 4848000,3);
    k4_final<<<(NC+127)/128, 512, 0, stream>>>(wsf+OFF_WT, wsf+OFF_AT, wsf+OFF_L, P.x[2], gamma, lbeta, out,
                                               200000, NC, 1, 3200000,1, 0,0, 0,0);
    k4_final<<<(NB+127)/128, 512, 0, stream>>>(wsf+OFF_WT, wsf+OFF_AT, wsf+OFF_L, P.x[3], gamma, lbeta, out,
                                               201000, NB, 1, 4816000,1, 0,0, 0,0);
}

// Round 5
// 1186.442 us; speedup vs baseline: 3.4196x; 1.0833x over previous
//
#include <hip/hip_runtime.h>
#include <hip/hip_bf16.h>
#include <math.h>

#define D 128

// problem sizes (fixed by reference)
#define NU 100000
#define NP 100000
#define NC 1000
#define NB 2000
#define NTOT 203000
#define EB 100000
#define ES 50000
#define ETOT 800000
#define NSEG 803000
#define NBLK 785          // ceil(NSEG/1024)

// ws layout (float offsets)
#define OFF_L    0            // 6448000 floats: low-rank accumulators
#define OFF_W0   6448000      // 10*3*128
#define OFF_BS   6451840      // 16 (bs[4])
#define OFF_WT   7251856      // 16384 floats: W_base^T
#define OFF_AT   7268240      // 8192 floats: A^T per phi
#define OFF_INT  7276432      // int region
// ints relative to (int*)(wsf+OFF_INT):
//   counts @ 0        (803000)
//   starts @ 803000   (803000)  -- after kscatter: segment END
//   srco   @ 1606000  (800000)  -- src | o<<17 | et<<19, CSR order
// bsums (785 ints) overlays OFF_L (only used before kagg rewrites L)

// per-edge-type metadata
__constant__ int c_srcT[10]   = {0,0,0,1,1,1,1,2,1,3};
__constant__ int c_phi [10]   = {0,0,0,1,1,1,1,2,1,3};
__constant__ int c_beta[10]   = {0,1,2,0,1,2,-1,-1,-1,-1};
__constant__ int c_E   [10]   = {EB,EB,EB,EB,EB,EB,ES,ES,ES,ES};
__constant__ int c_moff[10]   = {0,100000,200000,300000,400000,500000,600000,601000,701000,703000};

// per-dst-type gather config
__constant__ int g_nEt[4]     = {3,5,1,1};
__constant__ int g_ets[4][5]  = {{3,4,5,0,0},{0,1,2,7,9},{6,0,0,0,0},{8,0,0,0,0}};
__constant__ int g_gidx[4][5] = {{0,0,0,0,0},{0,0,0,1,2},{0,0,0,0,0},{0,0,0,0,0}};
__constant__ int g_nGrp[4]    = {1,3,1,1};
__constant__ int g_Loff[4][3] = {{1600000,0,0},{0,3216000,4848000},{3200000,0,0},{4816000,0,0}};

struct Ptrs {
    const float* x[4];
    const int*   ei[10];
    const int*   attr[4];   // for edge types 6..9
};

__device__ __forceinline__ void decode_et(int eflat, int& et, int& le) {
    if (eflat < 600000) { et = eflat / 100000; le = eflat - et * 100000; }
    else { int r = eflat - 600000; int q = r / 50000; et = 6 + q; le = r - q * 50000; }
}

// sum across the 16-lane quarter-wave group
__device__ __forceinline__ float qsum(float v) {
    v += __shfl_xor(v, 1, 64);
    v += __shfl_xor(v, 2, 64);
    v += __shfl_xor(v, 4, 64);
    v += __shfl_xor(v, 8, 64);
    return v;
}

// ---------------- K0: w0 tables + bs (softmax-invariant terms dropped) ----------------
__global__ void k0_tables(const float* __restrict__ Wb, const float* __restrict__ A,
                          const float* __restrict__ B, const float* __restrict__ behW,
                          const float* __restrict__ a_att,
                          float* __restrict__ w0, float* __restrict__ bs_out)
{
    __shared__ float a0[128];
    __shared__ float c0[128];
    __shared__ float g0[4][16];
    int t = threadIdx.x;
    if (t < 128) a0[t] = a_att[t];
    __syncthreads();
    if (t < 128) {
        float s0=0.f;
        for (int j=0;j<128;j++) s0 += Wb[j*128+t]*a0[j];
        c0[t]=s0;
    } else if (t < 192) {
        int q=t-128, p=q>>4, r=q&15;
        float s0=0.f;
        for (int i=0;i<128;i++) s0 += A[p*2048+i*16+r]*a0[i];
        g0[p][r]=s0;
    } else if (t < 196) {
        int b=t-192; float s=0.f;
        for (int i=0;i<128;i++) s += behW[b*128+i]*a_att[384+i];
        bs_out[b]=s;
    }
    __syncthreads();
    if (t < 128) {
        for (int et=0; et<10; ++et) {
            int phi=c_phi[et], beta=c_beta[et];
            if (beta >= 0) {
                float s0=c0[t];
                for (int r=0;r<16;r++) s0 += B[beta*2048+t*16+r]*g0[phi][r];
                w0[et*384+t]=s0; w0[et*384+128+t]=s0; w0[et*384+256+t]=s0;
            } else {
                for (int o=0;o<3;o++){
                    float s0=c0[t];
                    for (int r=0;r<16;r++) s0 += B[o*2048+t*16+r]*g0[phi][r];
                    w0[et*384+o*128+t]=s0;
                }
            }
        }
    }
}

// ---------------- ktrans: W_base^T and A^T precompute ----------------
__global__ __launch_bounds__(256) void ktrans(const float* __restrict__ Wb,
        const float* __restrict__ A, float* __restrict__ WbT, float* __restrict__ AT)
{
    int idx = blockIdx.x*256 + threadIdx.x;
    if (idx < 16384) { int i = idx>>7, j = idx&127; WbT[i*128+j] = Wb[j*128+i]; }
    int idx2 = idx - 16384;
    if (idx2 >= 0 && idx2 < 8192) {
        int p = idx2>>11, rem = idx2&2047, r = rem>>7, j = rem&127;
        AT[idx2] = A[p*2048 + j*16 + r];
    }
}

// ---------------- CSR build ----------------
__global__ __launch_bounds__(256) void khist(Ptrs P, int* __restrict__ counts)
{
    int eflat = blockIdx.x*256 + threadIdx.x;
    if (eflat >= ETOT) return;
    int et, le; decode_et(eflat, et, le);
    int dst = P.ei[et][c_E[et] + le];
    atomicAdd(&counts[c_moff[et] + dst], 1);
}

__global__ __launch_bounds__(256) void kscan1(const int* __restrict__ cnt,
                                              int* __restrict__ st, int* __restrict__ bsums)
{
    __shared__ int lds[256];
    int t = threadIdx.x, b = blockIdx.x;
    int base = b*1024 + t*4;
    int v0 = (base   < NSEG) ? cnt[base]   : 0;
    int v1 = (base+1 < NSEG) ? cnt[base+1] : 0;
    int v2 = (base+2 < NSEG) ? cnt[base+2] : 0;
    int v3 = (base+3 < NSEG) ? cnt[base+3] : 0;
    int s = v0+v1+v2+v3;
    lds[t] = s; __syncthreads();
    for (int off=1; off<256; off<<=1){
        int xv = (t>=off) ? lds[t-off] : 0;
        __syncthreads();
        lds[t] += xv;
        __syncthreads();
    }
    int incl = lds[t];
    int p = incl - s;
    if (t==255) bsums[b] = incl;
    if (base   < NSEG) st[base]   = p; p += v0;
    if (base+1 < NSEG) st[base+1] = p; p += v1;
    if (base+2 < NSEG) st[base+2] = p; p += v2;
    if (base+3 < NSEG) st[base+3] = p;
}

__global__ __launch_bounds__(256) void kscan2(int* __restrict__ bsums)
{
    __shared__ int lds[256];
    int t = threadIdx.x;
    int base = t*4;
    int v0 = (base   < NBLK) ? bsums[base]   : 0;
    int v1 = (base+1 < NBLK) ? bsums[base+1] : 0;
    int v2 = (base+2 < NBLK) ? bsums[base+2] : 0;
    int v3 = (base+3 < NBLK) ? bsums[base+3] : 0;
    int s = v0+v1+v2+v3;
    lds[t] = s; __syncthreads();
    for (int off=1; off<256; off<<=1){
        int xv = (t>=off) ? lds[t-off] : 0;
        __syncthreads();
        lds[t] += xv;
        __syncthreads();
    }
    int p = lds[t] - s;
    if (base   < NBLK) bsums[base]   = p; p += v0;
    if (base+1 < NBLK) bsums[base+1] = p; p += v1;
    if (base+2 < NBLK) bsums[base+2] = p; p += v2;
    if (base+3 < NBLK) bsums[base+3] = p;
}

__global__ __launch_bounds__(256) void kscan3(int* __restrict__ st, const int* __restrict__ bsums)
{
    int t = threadIdx.x, b = blockIdx.x;
    int add = bsums[b];
    int base = b*1024 + t*4;
    #pragma unroll
    for (int j=0;j<4;j++)
        if (base+j < NSEG) st[base+j] += add;
}

__global__ __launch_bounds__(256) void kscatter(Ptrs P, int* __restrict__ st, int* __restrict__ srco)
{
    int eflat = blockIdx.x*256 + threadIdx.x;
    if (eflat >= ETOT) return;
    int et, le; decode_et(eflat, et, le);
    const int* ei = P.ei[et];
    int E = c_E[et];
    int src = ei[le], dst = ei[E+le];
    int o = 0;
    if (et >= 6) { int a = P.attr[et-6][le]; o = min(max(a,0),2); }
    int pos = atomicAdd(&st[c_moff[et] + dst], 1);
    srco[pos] = src | (o<<17) | (et<<19);
}
// after kscatter: st[seg] == segment end; start = st[seg] - counts[seg]

// ---------------- kagg: one WAVE per node; fused logits + online softmax + aggregate --
// lane = 64-lane wave lane; grp = lane>>4 (edge slot 0..3); ln = lane&15 (feature chunk)
__global__ __launch_bounds__(256) void kagg(Ptrs P,
        const int* __restrict__ starts, const int* __restrict__ counts,
        const int* __restrict__ srco,
        const float* __restrict__ w0, const float* __restrict__ bs,
        const float* __restrict__ Bm,
        float* __restrict__ Sout, float* __restrict__ Lb, int nWaves)
{
    int lane = threadIdx.x & 63;
    int wv = (blockIdx.x * 256 + threadIdx.x) >> 6;
    int grp = lane >> 4, ln = lane & 15;
    float bs0 = bs[0], bs1 = bs[1], bs2 = bs[2];

    for (int nid = wv; nid < NTOT; nid += nWaves) {
        int T, n0;
        if (nid < NU) { T=0; n0=nid; }
        else if (nid < 200000) { T=1; n0=nid-100000; }
        else if (nid < 201000) { T=2; n0=nid-200000; }
        else { T=3; n0=nid-201000; }

        float Stot[8] = {0,0,0,0,0,0,0,0};
        float L0q[4] = {0,0,0,0}, L1q[4] = {0,0,0,0}, L2q[4] = {0,0,0,0};

        int nEt = g_nEt[T];
        for (int s=0; s<nEt; ++s) {
            int et = g_ets[T][s];
            int seg = c_moff[et] + n0;
            int cnt = counts[seg];
            if (cnt == 0) continue;
            int st0 = starts[seg] - cnt;
            bool structural = (et >= 6);
            const float* xs = P.x[c_srcT[et]];
            const float* wp = w0 + et*384;

            float m = -INFINITY, ssum = 0.f;
            float SA[8]={0,0,0,0,0,0,0,0}, SB[8]={0,0,0,0,0,0,0,0}, SC[8]={0,0,0,0,0,0,0,0};
            int fb=0, fc=0;

            for (int k0=0; k0<cnt; k0+=4) {
                bool act = (k0 + grp) < cnt;
                int sv = act ? srco[st0 + k0 + grp] : 0;
                int src = sv & 0x1FFFF, o = (sv>>17)&3;
                float4 hA, hB;
                if (act) {
                    const float* q = xs + (size_t)src*D + ln*8;
                    hA = *(const float4*)q; hB = *(const float4*)(q+4);
                } else { hA = make_float4(0.f,0.f,0.f,0.f); hB = hA; }
                const float* wq = wp + o*128 + ln*8;
                float4 wA = *(const float4*)wq, wB = *(const float4*)(wq+4);
                float d = hA.x*wA.x + hA.y*wA.y + hA.z*wA.z + hA.w*wA.w
                        + hB.x*wB.x + hB.y*wB.y + hB.z*wB.z + hB.w*wB.w;
                d = qsum(d);   // e for this slot, replicated over its 16 lanes
                float e;
                if (act) e = d + (structural ? (o==0?bs0:(o==1?bs1:bs2)) : 0.f);
                else     e = -INFINITY;

                // cross-slot max -> wave-uniform new running max
                float em = e;
                em = fmaxf(em, __shfl_xor(em, 16, 64));
                em = fmaxf(em, __shfl_xor(em, 32, 64));
                float mn = fmaxf(m, em);
                float sc = __expf(m - mn);   // m=-inf -> 0
                float wg = __expf(e - mn);   // e=-inf -> 0
                ssum = ssum*sc + wg;
                m = mn;

                float h[8] = {hA.x,hA.y,hA.z,hA.w,hB.x,hB.y,hB.z,hB.w};
                if (structural) {
                    #pragma unroll
                    for (int j=0;j<8;j++){ SA[j]*=sc; SB[j]*=sc; SC[j]*=sc; }
                    if (o == 0) {
                        #pragma unroll
                        for (int j=0;j<8;j++) SA[j] += wg*h[j];
                    } else if (o == 1) {
                        #pragma unroll
                        for (int j=0;j<8;j++) SB[j] += wg*h[j];
                        fb = 1;
                    } else {
                        #pragma unroll
                        for (int j=0;j<8;j++) SC[j] += wg*h[j];
                        fc = 1;
                    }
                } else {
                    #pragma unroll
                    for (int j=0;j<8;j++) SA[j] = SA[j]*sc + wg*h[j];
                }
            }

            // total ssum across the 4 slots
            float stt = ssum;
            stt += __shfl_xor(stt, 16, 64);
            stt += __shfl_xor(stt, 32, 64);
            float inv = 1.f/(stt + 1e-16f);

            int anyb = structural ? __any(fb) : 0;
            int anyc = structural ? __any(fc) : 0;

            // reduce buckets across slots (after: replicated over slots)
            #pragma unroll
            for (int j=0;j<8;j++){ SA[j] += __shfl_xor(SA[j],16,64); SA[j] += __shfl_xor(SA[j],32,64); }
            if (anyb) {
                #pragma unroll
                for (int j=0;j<8;j++){ SB[j] += __shfl_xor(SB[j],16,64); SB[j] += __shfl_xor(SB[j],32,64); }
            }
            if (anyc) {
                #pragma unroll
                for (int j=0;j<8;j++){ SC[j] += __shfl_xor(SC[j],16,64); SC[j] += __shfl_xor(SC[j],32,64); }
            }

            // B^T (rows ln*8..ln*8+7, cols grp*4..grp*4+3), then normalize
            float pr[4] = {0.f,0.f,0.f,0.f};
            if (structural) {
                #pragma unroll
                for (int j=0;j<8;j++)
                    Stot[j] += (SA[j] + SB[j] + SC[j]) * inv;
                {
                    const float* Bp = Bm + 0*2048 + grp*4;
                    #pragma unroll
                    for (int j=0;j<8;j++){
                        float4 b4 = *(const float4*)(Bp + (ln*8+j)*16);
                        pr[0]+=SA[j]*b4.x; pr[1]+=SA[j]*b4.y; pr[2]+=SA[j]*b4.z; pr[3]+=SA[j]*b4.w;
                    }
                }
                if (anyb) {
                    const float* Bp = Bm + 1*2048 + grp*4;
                    #pragma unroll
                    for (int j=0;j<8;j++){
                        float4 b4 = *(const float4*)(Bp + (ln*8+j)*16);
                        pr[0]+=SB[j]*b4.x; pr[1]+=SB[j]*b4.y; pr[2]+=SB[j]*b4.z; pr[3]+=SB[j]*b4.w;
                    }
                }
                if (anyc) {
                    const float* Bp = Bm + 2*2048 + grp*4;
                    #pragma unroll
                    for (int j=0;j<8;j++){
                        float4 b4 = *(const float4*)(Bp + (ln*8+j)*16);
                        pr[0]+=SC[j]*b4.x; pr[1]+=SC[j]*b4.y; pr[2]+=SC[j]*b4.z; pr[3]+=SC[j]*b4.w;
                    }
                }
            } else {
                #pragma unroll
                for (int j=0;j<8;j++) Stot[j] += SA[j] * inv;
                int beta = c_beta[et];
                const float* Bp = Bm + beta*2048 + grp*4;
                #pragma unroll
                for (int j=0;j<8;j++){
                    float4 b4 = *(const float4*)(Bp + (ln*8+j)*16);
                    pr[0]+=SA[j]*b4.x; pr[1]+=SA[j]*b4.y; pr[2]+=SA[j]*b4.z; pr[3]+=SA[j]*b4.w;
                }
            }
            // reduce pr within the 16-lane group; scale by inv
            #pragma unroll
            for (int q=0;q<4;q++) pr[q] = qsum(pr[q]) * inv;

            int gi = g_gidx[T][s];
            if (gi == 0) { L0q[0]+=pr[0]; L0q[1]+=pr[1]; L0q[2]+=pr[2]; L0q[3]+=pr[3]; }
            else if (gi == 1) { L1q[0]+=pr[0]; L1q[1]+=pr[1]; L1q[2]+=pr[2]; L1q[3]+=pr[3]; }
            else { L2q[0]+=pr[0]; L2q[1]+=pr[1]; L2q[2]+=pr[2]; L2q[3]+=pr[3]; }
        }

        if (grp == 0) {
            float* Srow = Sout + (size_t)nid*D + ln*8;
            *(float4*)Srow     = make_float4(Stot[0],Stot[1],Stot[2],Stot[3]);
            *(float4*)(Srow+4) = make_float4(Stot[4],Stot[5],Stot[6],Stot[7]);
        }
        if (ln < 4) {
            float v0 = (ln==0)?L0q[0]:(ln==1)?L0q[1]:(ln==2)?L0q[2]:L0q[3];
            Lb[g_Loff[T][0] + (size_t)n0*16 + grp*4 + ln] = v0;
            int ng = g_nGrp[T];
            if (ng > 1) {
                float v1 = (ln==0)?L1q[0]:(ln==1)?L1q[1]:(ln==2)?L1q[2]:L1q[3];
                Lb[g_Loff[T][1] + (size_t)n0*16 + grp*4 + ln] = v1;
            }
            if (ng > 2) {
                float v2 = (ln==0)?L2q[0]:(ln==1)?L2q[1]:(ln==2)?L2q[2]:L2q[3];
                Lb[g_Loff[T][2] + (size_t)n0*16 + grp*4 + ln] = v2;
            }
        }
    }
}

// ---------------- K4: all-LDS tiled  agg = W_base@S + sum A[p]@L_p, LN+ELU+residual ----
__global__ __launch_bounds__(512, 1) void k4_final(
        const float* __restrict__ WbT, const float* __restrict__ AT,
        const float* __restrict__ Lb, const float* __restrict__ x,
        const float* __restrict__ gamma, const float* __restrict__ lbeta,
        float* __restrict__ out, int rowStart, int nRows,
        int nPairs, int lo0, int ai0, int lo1, int ai1, int lo2, int ai2)
{
    __shared__ float st[128*132];   // S tile, stride 132
    __shared__ float wt[128*128];   // WbT tile: wt[i*128 + j]
    __shared__ float lt[128*52];    // L tile: lt[r*52 + pi*16 + k]
    int t = threadIdx.x;
    int r0 = blockIdx.x*128;

    for (int idx=t; idx<4096; idx+=512)
        *(float4*)&wt[idx*4] = *(const float4*)&WbT[idx*4];
    for (int idx=t; idx<4096; idx+=512){
        int r = idx>>5, i4 = idx&31;
        int lr = r0 + r;
        float4 v = (lr < nRows) ? *(const float4*)&out[(size_t)(rowStart+lr)*D + i4*4]
                                : make_float4(0.f,0.f,0.f,0.f);
        *(float4*)&st[r*132 + i4*4] = v;
    }
    for (int pi=0; pi<nPairs; ++pi){
        int lo = (pi==0)?lo0:((pi==1)?lo1:lo2);
        int r = t>>2, q = t&3;
        int lr = r0 + r;
        float4 v = (lr < nRows) ? *(const float4*)&Lb[lo + (size_t)lr*16 + q*4]
                                : make_float4(0.f,0.f,0.f,0.f);
        *(float4*)&lt[r*52 + pi*16 + q*4] = v;
    }
    __syncthreads();

    int cg = t & 15, rg = t >> 4;
    float acc[4][8];
    #pragma unroll
    for (int a=0;a<4;a++)
        #pragma unroll
        for (int c=0;c<8;c++) acc[a][c]=0.f;

    for (int i4=0; i4<32; ++i4){
        float4 sv0 = *(const float4*)&st[(rg*4+0)*132 + i4*4];
        float4 sv1 = *(const float4*)&st[(rg*4+1)*132 + i4*4];
        float4 sv2 = *(const float4*)&st[(rg*4+2)*132 + i4*4];
        float4 sv3 = *(const float4*)&st[(rg*4+3)*132 + i4*4];
        #pragma unroll
        for (int q=0;q<4;q++){
            float4 wA = *(const float4*)&wt[(i4*4+q)*128 + cg*4];
            float4 wB = *(const float4*)&wt[(i4*4+q)*128 + 64 + cg*4];
            float sq[4];
            sq[0] = (q==0)?sv0.x:(q==1)?sv0.y:(q==2)?sv0.z:sv0.w;
            sq[1] = (q==0)?sv1.x:(q==1)?sv1.y:(q==2)?sv1.z:sv1.w;
            sq[2] = (q==0)?sv2.x:(q==1)?sv2.y:(q==2)?sv2.z:sv2.w;
            sq[3] = (q==0)?sv3.x:(q==1)?sv3.y:(q==2)?sv3.z:sv3.w;
            #pragma unroll
            for (int rr=0;rr<4;rr++){
                acc[rr][0] += sq[rr]*wA.x;
                acc[rr][1] += sq[rr]*wA.y;
                acc[rr][2] += sq[rr]*wA.z;
                acc[rr][3] += sq[rr]*wA.w;
                acc[rr][4] += sq[rr]*wB.x;
                acc[rr][5] += sq[rr]*wB.y;
                acc[rr][6] += sq[rr]*wB.z;
                acc[rr][7] += sq[rr]*wB.w;
            }
        }
    }

    for (int pi=0; pi<nPairs; ++pi){
        int ai = (pi==0)?ai0:((pi==1)?ai1:ai2);
        const float* Ap = AT + ai*2048;
        #pragma unroll 4
        for (int r=0;r<16;++r){
            float4 aA = *(const float4*)&Ap[r*128 + cg*4];
            float4 aB = *(const float4*)&Ap[r*128 + 64 + cg*4];
            float lv[4];
            #pragma unroll
            for (int rr=0;rr<4;rr++) lv[rr] = lt[(rg*4+rr)*52 + pi*16 + r];
            #pragma unroll
            for (int rr=0;rr<4;rr++){
                acc[rr][0] += lv[rr]*aA.x;
                acc[rr][1] += lv[rr]*aA.y;
                acc[rr][2] += lv[rr]*aA.z;
                acc[rr][3] += lv[rr]*aA.w;
                acc[rr][4] += lv[rr]*aB.x;
                acc[rr][5] += lv[rr]*aB.y;
                acc[rr][6] += lv[rr]*aB.z;
                acc[rr][7] += lv[rr]*aB.w;
            }
        }
    }

    int jA = cg*4, jB = 64 + cg*4;
    float4 gA = *(const float4*)&gamma[jA], gB = *(const float4*)&gamma[jB];
    float4 bA = *(const float4*)&lbeta[jA], bB = *(const float4*)&lbeta[jB];
    float gv[8] = {gA.x,gA.y,gA.z,gA.w,gB.x,gB.y,gB.z,gB.w};
    float bv[8] = {bA.x,bA.y,bA.z,bA.w,bB.x,bB.y,bB.z,bB.w};

    #pragma unroll
    for (int rr=0;rr<4;rr++){
        int lr = r0 + rg*4 + rr;
        float lsum=0.f, lsq=0.f;
        #pragma unroll
        for (int c=0;c<8;c++){ lsum += acc[rr][c]; lsq += acc[rr][c]*acc[rr][c]; }
        #pragma unroll
        for (int mm=1; mm<16; mm<<=1){ lsum += __shfl_xor(lsum,mm,64); lsq += __shfl_xor(lsq,mm,64); }
        if (lr >= nRows) continue;
        float mu = lsum*(1.f/128.f);
        float var = lsq*(1.f/128.f) - mu*mu;
        float rstd = rsqrtf(var + 1e-5f);
        const float* xr = x + (size_t)lr*D;
        float4 xA = *(const float4*)(xr+jA), xB = *(const float4*)(xr+jB);
        float xv[8] = {xA.x,xA.y,xA.z,xA.w,xB.x,xB.y,xB.z,xB.w};
        float ov[8];
        #pragma unroll
        for (int c=0;c<8;c++){
            float hn = (acc[rr][c]-mu)*rstd*gv[c] + bv[c];
            float z = hn + xv[c];
            ov[c] = z > 0.f ? z : expm1f(z);
        }
        float* orow = out + (size_t)(rowStart+lr)*D;
        *(float4*)(orow+jA) = make_float4(ov[0],ov[1],ov[2],ov[3]);
        *(float4*)(orow+jB) = make_float4(ov[4],ov[5],ov[6],ov[7]);
    }
}

extern "C" void kernel_launch(void* const* d_in, const int* in_sizes, int n_in,
                              void* d_out, int out_size, void* d_ws, size_t ws_size,
                              hipStream_t stream)
{
    (void)in_sizes; (void)n_in; (void)out_size; (void)ws_size;
    Ptrs P;
    P.x[0] = (const float*)d_in[0];   // x_user
    P.x[1] = (const float*)d_in[1];   // x_product
    P.x[2] = (const float*)d_in[2];   // x_category
    P.x[3] = (const float*)d_in[3];   // x_brand
    P.ei[0] = (const int*)d_in[4];    // view
    P.ei[1] = (const int*)d_in[5];    // cart
    P.ei[2] = (const int*)d_in[6];    // purchase
    P.ei[3] = (const int*)d_in[7];    // rev_view
    P.ei[4] = (const int*)d_in[8];    // rev_cart
    P.ei[5] = (const int*)d_in[9];    // rev_purchase
    P.ei[6] = (const int*)d_in[10];   // belongs_to
    P.attr[0] = (const int*)d_in[11];
    P.ei[7] = (const int*)d_in[12];   // contains
    P.attr[1] = (const int*)d_in[13];
    P.ei[8] = (const int*)d_in[14];   // producedBy
    P.attr[2] = (const int*)d_in[15];
    P.ei[9] = (const int*)d_in[16];   // brands
    P.attr[3] = (const int*)d_in[17];
    const float* Wb    = (const float*)d_in[18];
    const float* A     = (const float*)d_in[19];
    const float* B     = (const float*)d_in[20];
    const float* behW  = (const float*)d_in[22];
    const float* a_att = (const float*)d_in[23];
    const float* gamma = (const float*)d_in[24];
    const float* lbeta = (const float*)d_in[25];
    float* wsf = (float*)d_ws;
    float* out = (float*)d_out;

    int* ip     = (int*)(wsf + OFF_INT);
    int* counts = ip;
    int* starts = ip + 803000;
    int* srco   = ip + 1606000;
    int* bsums  = (int*)wsf;          // overlays L region, used only pre-kagg

    hipMemsetAsync(counts, 0, (size_t)NSEG*sizeof(int), stream);

    k0_tables<<<1, 256, 0, stream>>>(Wb, A, B, behW, a_att, wsf+OFF_W0, wsf+OFF_BS);
    ktrans<<<96, 256, 0, stream>>>(Wb, A, wsf+OFF_WT, wsf+OFF_AT);
    khist<<<3125, 256, 0, stream>>>(P, counts);
    kscan1<<<NBLK, 256, 0, stream>>>(counts, starts, bsums);
    kscan2<<<1, 256, 0, stream>>>(bsums);
    kscan3<<<NBLK, 256, 0, stream>>>(starts, bsums);
    kscatter<<<3125, 256, 0, stream>>>(P, starts, srco);

    kagg<<<2048, 256, 0, stream>>>(P, starts, counts, srco,
                                   wsf+OFF_W0, wsf+OFF_BS, B,
                                   out, wsf+OFF_L, 2048*4);

    k4_final<<<(NU+127)/128, 512, 0, stream>>>(wsf+OFF_WT, wsf+OFF_AT, wsf+OFF_L, P.x[0], gamma, lbeta, out,
                                               0,      NU, 1, 1600000,1, 0,0, 0,0);
    k4_final<<<(NP+127)/128, 512, 0, stream>>>(wsf+OFF_WT, wsf+OFF_AT, wsf+OFF_L, P.x[1], gamma, lbeta, out,
                                               100000, NP, 3, 0,0, 3216000,2, 4848000,3);
    k4_final<<<(NC+127)/128, 512, 0, stream>>>(wsf+OFF_WT, wsf+OFF_AT, wsf+OFF_L, P.x[2], gamma, lbeta, out,
                                               200000, NC, 1, 3200000,1, 0,0, 0,0);
    k4_final<<<(NB+127)/128, 512, 0, stream>>>(wsf+OFF_WT, wsf+OFF_AT, wsf+OFF_L, P.x[3], gamma, lbeta, out,
                                               201000, NB, 1, 4816000,1, 0,0, 0,0);
}